// Round 14
// baseline (482.339 us; speedup 1.0000x reference)
//
#include <hip/hip_runtime.h>

typedef unsigned short u16;
typedef unsigned int u32;
typedef short bf16x8 __attribute__((ext_vector_type(8)));
typedef float f32x4 __attribute__((ext_vector_type(4)));

// ---------------- threefry2x32 (JAX-compatible, 20 rounds) ----------------
__host__ __device__ inline u32 rotl32(u32 x, int r) { return (x << r) | (x >> (32 - r)); }

__host__ __device__ inline void tf_r4(u32& x0, u32& x1, int r0, int r1, int r2, int r3) {
  x0 += x1; x1 = rotl32(x1, r0); x1 ^= x0;
  x0 += x1; x1 = rotl32(x1, r1); x1 ^= x0;
  x0 += x1; x1 = rotl32(x1, r2); x1 ^= x0;
  x0 += x1; x1 = rotl32(x1, r3); x1 ^= x0;
}

__host__ __device__ inline void tf2x32(u32 k0, u32 k1, u32 c0, u32 c1, u32* o0, u32* o1) {
  u32 ks2 = 0x1BD11BDAu ^ k0 ^ k1;
  u32 x0 = c0 + k0, x1 = c1 + k1;
  tf_r4(x0, x1, 13, 15, 26, 6);  x0 += k1;  x1 += ks2 + 1u;
  tf_r4(x0, x1, 17, 29, 16, 24); x0 += ks2; x1 += k0 + 2u;
  tf_r4(x0, x1, 13, 15, 26, 6);  x0 += k0;  x1 += k1 + 3u;
  tf_r4(x0, x1, 17, 29, 16, 24); x0 += k1;  x1 += ks2 + 4u;
  tf_r4(x0, x1, 13, 15, 26, 6);  x0 += ks2; x1 += k0 + 5u;
  *o0 = x0; *o1 = x1;
}

// XLA/Giles f32 erfinv
__device__ inline float erfinv_f(float x) {
  float w = -log1pf(-x * x);
  float p;
  if (w < 5.0f) {
    w -= 2.5f;
    p = 2.81022636e-08f;
    p = 3.43273939e-07f + p * w;
    p = -3.5233877e-06f + p * w;
    p = -4.39150654e-06f + p * w;
    p = 0.00021858087f + p * w;
    p = -0.00125372503f + p * w;
    p = -0.00417768164f + p * w;
    p = 0.246640727f + p * w;
    p = 1.50140941f + p * w;
  } else {
    w = sqrtf(w) - 3.0f;
    p = -0.000200214257f;
    p = 0.000100950558f + p * w;
    p = 0.00134934322f + p * w;
    p = -0.00367342844f + p * w;
    p = 0.00573950773f + p * w;
    p = -0.0076224613f + p * w;
    p = 0.00943887047f + p * w;
    p = 1.00167406f + p * w;
    p = 2.83297682f + p * w;
  }
  return p * x;
}

__device__ inline float bits2normal(u32 b) {
  float f = __uint_as_float((b >> 9) | 0x3F800000u) - 1.0f;  // [0,1)
  float u = f * 2.0f - 0.99999994f;
  u = fmaxf(u, -0.99999994f);
  return 1.41421356f * erfinv_f(u);
}

// ---------------- dtype helpers ----------------
__device__ inline void stor(u16* p, float v) {
  u32 x = __float_as_uint(v);
  *p = (u16)((x + 0x7FFFu + ((x >> 16) & 1u)) >> 16);  // RTNE bf16
}
__device__ inline u16 f2b(float v) {
  u32 x = __float_as_uint(v);
  return (u16)((x + 0x7FFFu + ((x >> 16) & 1u)) >> 16);
}
__device__ inline float blo(u32 w) { return __uint_as_float(w << 16); }
__device__ inline float bhi(u32 w) { return __uint_as_float(w & 0xFFFF0000u); }

// ---------------- fused prep A: count + std1 + clean transposes + x cast ----------------
__global__ __launch_bounds__(256) void k_prepA(const int* __restrict__ ei, int* __restrict__ cnt, int E,
                                               const float* __restrict__ W1, const float* __restrict__ b1,
                                               const float* __restrict__ W2, const float* __restrict__ b2,
                                               double* __restrict__ psd,
                                               const float* __restrict__ Wd,
                                               u16* __restrict__ W1T, u16* __restrict__ W2T, u16* __restrict__ WdT,
                                               const float* __restrict__ x, u16* __restrict__ xb,
                                               int N, int c1) {
  __shared__ double sh[256];
  __shared__ double sh2[256];
  int b = blockIdx.x;
  if (b < c1) {  // degree count
    int e = b * 256 + threadIdx.x;
    if (e < E) atomicAdd(&cnt[ei[E + e]], 1);
    return;
  }
  b -= c1;
  if (b < 64) {  // std1: 4 tensors x 16 chunks
    int t = b >> 4, ch = b & 15;
    const float* p; int n;
    if (t == 0) { p = W1; n = 128 * 512; }
    else if (t == 1) { p = b1; n = 512; }
    else if (t == 2) { p = W2; n = 512 * 256; }
    else { p = b2; n = 256; }
    int s0 = (int)((long long)n * ch / 16), s1 = (int)((long long)n * (ch + 1) / 16);
    double s = 0.0, ss = 0.0;
    for (int i = s0 + threadIdx.x; i < s1; i += 256) { double v = p[i]; s += v; ss += v * v; }
    sh[threadIdx.x] = s; sh2[threadIdx.x] = ss;
    __syncthreads();
    for (int o = 128; o > 0; o >>= 1) {
      if (threadIdx.x < o) { sh[threadIdx.x] += sh[threadIdx.x + o]; sh2[threadIdx.x] += sh2[threadIdx.x + o]; }
      __syncthreads();
    }
    if (threadIdx.x == 0) { psd[b * 2] = sh[0]; psd[b * 2 + 1] = sh2[0]; }
    return;
  }
  b -= 64;
  if (b < 256) {  // W1T: f32 [128][512] -> bf16 [512][128]
    int j = b * 256 + threadIdx.x;
    int k = j >> 9, n = j & 511;
    W1T[(size_t)n * 128 + k] = f2b(W1[j]);
    return;
  }
  b -= 256;
  if (b < 512) {  // W2T: [512][256] -> [256][512]
    int j = b * 256 + threadIdx.x;
    int k = j >> 8, n = j & 255;
    W2T[(size_t)n * 512 + k] = f2b(W2[j]);
    return;
  }
  b -= 512;
  if (b < 128) {  // WdT: [256][128] -> [128][256]
    int j = b * 256 + threadIdx.x;
    int k = j >> 7, n = j & 127;
    WdT[(size_t)n * 256 + k] = f2b(Wd[j]);
    return;
  }
  b -= 128;
  {  // xb cast: 4 f32 per thread
    int j = b * 256 + threadIdx.x;
    int n4 = N * 128 / 4;
    if (j < n4) {
      float4 v = ((const float4*)x)[j];
      ((u32*)xb)[j * 2] = ((u32)f2b(v.x)) | (((u32)f2b(v.y)) << 16);
      ((u32*)xb)[j * 2 + 1] = ((u32)f2b(v.z)) | (((u32)f2b(v.w)) << 16);
    }
  }
}

// ---------------- graph preprocessing ----------------
__global__ __launch_bounds__(1024) void k_scan_local(const int* __restrict__ cnt,
                                                     int* __restrict__ incl, int* __restrict__ bsum,
                                                     int n) {
  __shared__ int buf[1024];
  int i = blockIdx.x * 1024 + threadIdx.x;
  int v = (i < n) ? cnt[i] : 0;
  buf[threadIdx.x] = v;
  __syncthreads();
  for (int off = 1; off < 1024; off <<= 1) {
    int t = (threadIdx.x >= off) ? buf[threadIdx.x - off] : 0;
    __syncthreads();
    buf[threadIdx.x] += t;
    __syncthreads();
  }
  if (i < n) incl[i] = buf[threadIdx.x];
  if (threadIdx.x == 1023) bsum[blockIdx.x] = buf[1023];
}

// block 0: exclusive-scan bsum; block 1: std2 finalize
__global__ __launch_bounds__(256) void k_small2(int* __restrict__ bsum, int nb,
                                                const double* __restrict__ psd, float* __restrict__ sigma) {
  if (blockIdx.x == 0) {
    __shared__ int buf[256];
    int v = (threadIdx.x < nb) ? bsum[threadIdx.x] : 0;
    buf[threadIdx.x] = v;
    __syncthreads();
    for (int off = 1; off < 256; off <<= 1) {
      int t = (threadIdx.x >= off) ? buf[threadIdx.x - off] : 0;
      __syncthreads();
      buf[threadIdx.x] += t;
      __syncthreads();
    }
    if (threadIdx.x < nb) bsum[threadIdx.x] = buf[threadIdx.x] - v;  // exclusive
  } else {
    int l = threadIdx.x;
    if (l < 64) {
      double s = psd[l * 2], ss = psd[l * 2 + 1];
      for (int off = 1; off < 16; off <<= 1) { s += __shfl_xor(s, off); ss += __shfl_xor(ss, off); }
      if ((l & 15) == 0) {
        int t = l >> 4;
        int n = (t == 0) ? 128 * 512 : (t == 1) ? 512 : (t == 2) ? 512 * 256 : 256;
        double mean = s / n;
        double var = (ss - s * mean) / (double)(n - 1);
        if (var < 0.0) var = 0.0;
        sigma[t] = fmaxf((float)sqrt(var), 1e-6f);
      }
    }
  }
}

__global__ __launch_bounds__(1024) void k_scan_final(const int* __restrict__ cnt,
                                                     const int* __restrict__ incl,
                                                     const int* __restrict__ bsum,
                                                     int* __restrict__ row_ptr, int* __restrict__ cursor,
                                                     float* __restrict__ dinv, int n, int E) {
  int i = blockIdx.x * 1024 + threadIdx.x;
  if (i < n) {
    int c = cnt[i];
    int ex = incl[i] + bsum[blockIdx.x] - c;
    row_ptr[i] = ex;
    cursor[i] = ex;
    dinv[i] = 1.0f / sqrtf((float)(c + 1));  // deg includes self-loop
  }
  if (i == 0) row_ptr[n] = E;
}

__global__ void k_place(const int* __restrict__ ei, int* __restrict__ cursor,
                        const float* __restrict__ dinv, int* __restrict__ src_sorted,
                        float* __restrict__ w_sorted, int E) {
  int e = blockIdx.x * blockDim.x + threadIdx.x;
  if (e < E) {
    int s = ei[e], d = ei[E + e];
    int slot = atomicAdd(&cursor[d], 1);
    src_sorted[slot] = s;
    w_sorted[slot] = dinv[s] * dinv[d];
  }
}

// ---------------- fused: perturbAll (blocks 0..770) + agg_px (rest) ----------------
__global__ __launch_bounds__(256) void k_pxper(const float* __restrict__ W1, const float* __restrict__ b1,
                                               const float* __restrict__ W2, const float* __restrict__ b2,
                                               u16* __restrict__ W1hT, float* __restrict__ b1h,
                                               u16* __restrict__ W2hT, float* __restrict__ b2h,
                                               float* __restrict__ bcat,
                                               const float* __restrict__ sigma,
                                               u32 k00, u32 k01, u32 k10, u32 k11,
                                               u32 k20, u32 k21, u32 k30, u32 k31,
                                               const u16* __restrict__ xb, u16* __restrict__ px,
                                               const int* __restrict__ rp, const int* __restrict__ src,
                                               const float* __restrict__ wst, const float* __restrict__ dinv,
                                               int n) {
  int b = blockIdx.x;
  u32 r0, r1;
  if (b < 256) {  // W1 [128][512]
    int j = b * 256 + threadIdx.x;
    tf2x32(k00, k01, 0u, (u32)j, &r0, &r1);
    float v = W1[j] + sigma[0] * bits2normal(r0 ^ r1);
    int k = j >> 9, nn = j & 511;
    W1hT[(size_t)nn * 128 + k] = f2b(v);
    return;
  }
  b -= 256;
  if (b < 2) {  // b1 [512]
    int j = b * 256 + threadIdx.x;
    tf2x32(k10, k11, 0u, (u32)j, &r0, &r1);
    b1h[j] = b1[j] + sigma[1] * bits2normal(r0 ^ r1);
    return;
  }
  b -= 2;
  if (b < 512) {  // W2 [512][256]
    int j = b * 256 + threadIdx.x;
    tf2x32(k20, k21, 0u, (u32)j, &r0, &r1);
    float v = W2[j] + sigma[2] * bits2normal(r0 ^ r1);
    int k = j >> 8, nn = j & 255;
    W2hT[(size_t)nn * 512 + k] = f2b(v);
    return;
  }
  b -= 512;
  if (b < 1) {  // b2 [256] + bcat
    int j = threadIdx.x;
    tf2x32(k30, k31, 0u, (u32)j, &r0, &r1);
    float v = b2[j] + sigma[3] * bits2normal(r0 ^ r1);
    b2h[j] = v;
    bcat[256 + j] = v;
    bcat[j] = b2[j];
    return;
  }
  b -= 1;
  // ---- agg_px part ----
  int wv = threadIdx.x >> 6, lane = threadIdx.x & 63;
  int node = b * 4 + wv;
  if (node >= n) return;
  float a0 = 0.f, a1 = 0.f;
  int s0 = rp[node], s1 = rp[node + 1];
  int s = s0;
  for (; s + 8 <= s1; s += 8) {
    u32 v[8]; float wg[8];
#pragma unroll
    for (int u = 0; u < 8; ++u) {
      int r = src[s + u];
      wg[u] = wst[s + u];
      v[u] = *((const u32*)(xb + (size_t)r * 128) + lane);
    }
#pragma unroll
    for (int u = 0; u < 8; ++u) { a0 += wg[u] * blo(v[u]); a1 += wg[u] * bhi(v[u]); }
  }
  for (; s < s1; ++s) {
    float wgt = wst[s];
    int r = src[s];
    u32 w = *((const u32*)(xb + (size_t)r * 128) + lane);
    a0 += wgt * blo(w); a1 += wgt * bhi(w);
  }
  float sw = dinv[node]; sw *= sw;
  u32 w = *((const u32*)(xb + (size_t)node * 128) + lane);
  a0 += sw * blo(w); a1 += sw * bhi(w);
  u32 o = ((u32)f2b(a0)) | (((u32)f2b(a1)) << 16);
  *((u32*)(px + (size_t)node * 128) + lane) = o;
}

// ---------------- L1 GEMM: A-resident column-loop (unchanged from R13) ----------------
__global__ __launch_bounds__(256) void k_mgemmL1(const u16* __restrict__ A,
                                                 const u16* __restrict__ BT0, const u16* __restrict__ BT1,
                                                 const float* __restrict__ bias0, const float* __restrict__ bias1,
                                                 u16* __restrict__ C0, u16* __restrict__ C1,
                                                 int M) {
  __shared__ u16 As[16384];
  __shared__ u16 Bs[16384];
  const u16* BT = blockIdx.y ? BT1 : BT0;
  const float* bias = blockIdx.y ? bias1 : bias0;
  u16* C = blockIdx.y ? C1 : C0;
  const int t = threadIdx.x;
  const int w = t >> 6, lane = t & 63;
  const int brow = blockIdx.x * 128;
  const int wr = w >> 1, wc = w & 1;

#pragma unroll
  for (int j = 0; j < 8; ++j) {
    int c = j * 4 + w;
    int lc = c * 64 + lane;
    int row = lc >> 4, ch = lc & 15;
    int chs = ch ^ (row & 15);
    int ar = brow + row; if (ar > M - 1) ar = M - 1;
    __builtin_amdgcn_global_load_lds(
        (const __attribute__((address_space(1))) void*)(A + (size_t)ar * 128 + chs * 8),
        (__attribute__((address_space(3))) void*)(As + c * 512), 16, 0, 0);
  }

  for (int cb = 0; cb < 4; ++cb) {
    int bcol = cb * 128;
#pragma unroll
    for (int j = 0; j < 8; ++j) {
      int c = j * 4 + w;
      int lc = c * 64 + lane;
      int row = lc >> 4, ch = lc & 15;
      int chs = ch ^ (row & 15);
      __builtin_amdgcn_global_load_lds(
          (const __attribute__((address_space(1))) void*)(BT + (size_t)(bcol + row) * 128 + chs * 8),
          (__attribute__((address_space(3))) void*)(Bs + c * 512), 16, 0, 0);
    }
    __syncthreads();

    f32x4 acc[4][4];
#pragma unroll
    for (int m = 0; m < 4; ++m)
#pragma unroll
      for (int n = 0; n < 4; ++n) acc[m][n] = (f32x4){0.f, 0.f, 0.f, 0.f};

#pragma unroll
    for (int kk = 0; kk < 4; ++kk) {
      int ch = kk * 4 + (lane >> 4);
      bf16x8 af[4], bb[4];
#pragma unroll
      for (int m = 0; m < 4; ++m) {
        int row = wr * 64 + m * 16 + (lane & 15);
        af[m] = *(const bf16x8*)(As + row * 128 + ((ch ^ (row & 15)) << 3));
      }
#pragma unroll
      for (int n = 0; n < 4; ++n) {
        int row = wc * 64 + n * 16 + (lane & 15);
        bb[n] = *(const bf16x8*)(Bs + row * 128 + ((ch ^ (row & 15)) << 3));
      }
#pragma unroll
      for (int m = 0; m < 4; ++m)
#pragma unroll
        for (int n = 0; n < 4; ++n)
          acc[m][n] = __builtin_amdgcn_mfma_f32_16x16x32_bf16(af[m], bb[n], acc[m][n], 0, 0, 0);
    }
    __syncthreads();

    u16* wlds = Bs + w * 4096;
#pragma unroll
    for (int m = 0; m < 4; ++m) {
      int lr0 = m * 16 + (lane >> 4) * 4;
#pragma unroll
      for (int n = 0; n < 4; ++n) {
        int lc = n * 16 + (lane & 15);
        float bv = bias[bcol + wc * 64 + lc];
        int chunk = lc >> 3, wi = lc & 7;
#pragma unroll
        for (int q = 0; q < 4; ++q) {
          int lr = lr0 + q;
          float v = fmaxf(acc[m][n][q] + bv, 0.0f);
          wlds[lr * 64 + ((chunk ^ (lr & 7)) << 3) + wi] = f2b(v);
        }
      }
    }
    int sr = lane >> 3, sc = lane & 7;
#pragma unroll
    for (int i = 0; i < 8; ++i) {
      int lr = i * 8 + sr;
      int gr = brow + wr * 64 + lr;
      if (gr < M) {
        uint4 vv = *(const uint4*)(wlds + lr * 64 + ((sc ^ (lr & 7)) << 3));
        *(uint4*)(C + (size_t)gr * 512 + bcol + wc * 64 + sc * 8) = vv;
      }
    }
    __syncthreads();
  }
}

// ---------------- MFMA tile body, 2-PHASE double-buffered (L2 + decoder) ----------------
// Four statically distinct LDS buffers -> compiler can prove ds_read(cur) doesn't alias
// in-flight global_load_lds(next); stage(t+1) issued BEFORE compute(t) so HBM latency
// hides under MFMA. One barrier per phase. K/64 must be even (512, 256 both are).
template <bool RELU, bool BIAS>
__device__ inline void mgemm_tile_db(u16* __restrict__ As0, u16* __restrict__ Bs0,
                                     u16* __restrict__ As1, u16* __restrict__ Bs1,
                                     const u16* __restrict__ A, const u16* __restrict__ BT,
                                     const float* __restrict__ bias, u16* __restrict__ C,
                                     int M, int K, int ldc, int coloff, int bx, int by) {
  const int t = threadIdx.x;
  const int w = t >> 6, lane = t & 63;
  const int brow = by * 128;
  const int bcol = bx * 128;
  const int wr = w >> 1, wc = w & 1;

  f32x4 acc[4][4];
#pragma unroll
  for (int m = 0; m < 4; ++m)
#pragma unroll
    for (int n = 0; n < 4; ++n) acc[m][n] = (f32x4){0.f, 0.f, 0.f, 0.f};

  auto stage = [&](u16* __restrict__ Asb, u16* __restrict__ Bsb, int kt) {
#pragma unroll
    for (int j = 0; j < 4; ++j) {
      int c = j * 4 + w;
      int li = c * 64 + lane;
      int row = li >> 3, col8 = li & 7;
      int col8s = col8 ^ (row & 7);
      int ar = brow + row; if (ar > M - 1) ar = M - 1;
      __builtin_amdgcn_global_load_lds(
          (const __attribute__((address_space(1))) void*)(A + (size_t)ar * K + kt + col8s * 8),
          (__attribute__((address_space(3))) void*)(Asb + c * 512), 16, 0, 0);
      __builtin_amdgcn_global_load_lds(
          (const __attribute__((address_space(1))) void*)(BT + (size_t)(bcol + row) * K + kt + col8s * 8),
          (__attribute__((address_space(3))) void*)(Bsb + c * 512), 16, 0, 0);
    }
  };

  auto compute = [&](const u16* __restrict__ Asb, const u16* __restrict__ Bsb) {
    bf16x8 af[4][2], bb[4][2];
#pragma unroll
    for (int kk = 0; kk < 2; ++kk) {
      int ch = kk * 4 + (lane >> 4);
      int chs = ch ^ (lane & 7);
#pragma unroll
      for (int m = 0; m < 4; ++m)
        af[m][kk] = *(const bf16x8*)(Asb + (wr * 64 + m * 16 + (lane & 15)) * 64 + chs * 8);
#pragma unroll
      for (int n = 0; n < 4; ++n)
        bb[n][kk] = *(const bf16x8*)(Bsb + (wc * 64 + n * 16 + (lane & 15)) * 64 + chs * 8);
    }
#pragma unroll
    for (int kk = 0; kk < 2; ++kk)
#pragma unroll
      for (int m = 0; m < 4; ++m)
#pragma unroll
        for (int n = 0; n < 4; ++n)
          acc[m][n] = __builtin_amdgcn_mfma_f32_16x16x32_bf16(af[m][kk], bb[n][kk], acc[m][n], 0, 0, 0);
  };

  stage(As0, Bs0, 0);
  __syncthreads();
  for (int kt = 0; kt < K; kt += 128) {
    if (kt + 64 < K) stage(As1, Bs1, kt + 64);
    compute(As0, Bs0);
    __syncthreads();
    if (kt + 128 < K) stage(As0, Bs0, kt + 128);
    if (kt + 64 < K) compute(As1, Bs1);
    __syncthreads();
  }

  // epilogue: per-wave 64x64 scratch in As0/Bs0 (all reads drained by final barrier)
  u16* wlds = ((w & 2) ? Bs0 : As0) + (w & 1) * 4096;
#pragma unroll
  for (int m = 0; m < 4; ++m) {
    int lr0 = m * 16 + (lane >> 4) * 4;
#pragma unroll
    for (int n = 0; n < 4; ++n) {
      int lc = n * 16 + (lane & 15);
      float bv = BIAS ? bias[bcol + wc * 64 + lc] : 0.0f;
      int chunk = lc >> 3, wi = lc & 7;
#pragma unroll
      for (int q = 0; q < 4; ++q) {
        int lr = lr0 + q;
        float v = acc[m][n][q] + bv;
        if (RELU) v = fmaxf(v, 0.0f);
        wlds[lr * 64 + ((chunk ^ (lr & 7)) << 3) + wi] = f2b(v);
      }
    }
  }
  int sr = lane >> 3, sc = lane & 7;
#pragma unroll
  for (int i = 0; i < 8; ++i) {
    int lr = i * 8 + sr;
    int gr = brow + wr * 64 + lr;
    if (gr < M) {
      uint4 vv = *(const uint4*)(wlds + lr * 64 + ((sc ^ (lr & 7)) << 3));
      *(uint4*)(C + (size_t)gr * ldc + coloff + bcol + wc * 64 + sc * 8) = vv;
    }
  }
}

// dual-branch GEMM (L2): blockIdx.z selects branch
template <bool RELU, bool BIAS>
__global__ __launch_bounds__(256) void k_mgemm2(const u16* A0, const u16* A1,
                                                const u16* BT0, const u16* BT1,
                                                const float* bias0, const float* bias1,
                                                u16* C0, u16* C1,
                                                int M, int K, int ldc, int co0, int co1) {
  __shared__ u16 As0[8192];
  __shared__ u16 Bs0[8192];
  __shared__ u16 As1[8192];
  __shared__ u16 Bs1[8192];
  int z = blockIdx.z;
  mgemm_tile_db<RELU, BIAS>(As0, Bs0, As1, Bs1,
                            z ? A1 : A0, z ? BT1 : BT0, z ? bias1 : bias0,
                            z ? C1 : C0, M, K, ldc, z ? co1 : co0, blockIdx.x, blockIdx.y);
}

// single-branch GEMM (decoder)
__global__ __launch_bounds__(256) void k_mgemm1(const u16* __restrict__ A, const u16* __restrict__ BT,
                                                u16* __restrict__ C, int M) {
  __shared__ u16 As0[8192];
  __shared__ u16 Bs0[8192];
  __shared__ u16 As1[8192];
  __shared__ u16 Bs1[8192];
  mgemm_tile_db<false, false>(As0, Bs0, As1, Bs1, A, BT, nullptr, C, M, 256, 128, 0, 0, blockIdx.x);
}

// ---------------- merged layer-2 agg (4-deep unroll) ----------------
__global__ __launch_bounds__(256) void k_agg512(const u16* __restrict__ ycat,
                                                float* __restrict__ zc, u16* __restrict__ zcb,
                                                float* __restrict__ zh,
                                                const int* __restrict__ rp, const int* __restrict__ src,
                                                const float* __restrict__ wst, const float* __restrict__ dinv,
                                                const float* __restrict__ bcat, int n) {
  int wv = threadIdx.x >> 6, lane = threadIdx.x & 63;
  int node = blockIdx.x * 4 + wv;
  if (node >= n) return;
  float acc[8] = {};
  int s0 = rp[node], s1 = rp[node + 1];
  int s = s0;
  for (; s + 4 <= s1; s += 4) {
    uint4 v[4]; float wg[4];
#pragma unroll
    for (int u = 0; u < 4; ++u) {
      int r = src[s + u];
      wg[u] = wst[s + u];
      v[u] = *((const uint4*)(ycat + (size_t)r * 512) + lane);
    }
#pragma unroll
    for (int u = 0; u < 4; ++u)
#pragma unroll
      for (int q = 0; q < 4; ++q) {
        u32 word = ((const u32*)&v[u])[q];
        acc[2 * q]     += wg[u] * blo(word);
        acc[2 * q + 1] += wg[u] * bhi(word);
      }
  }
  for (; s < s1; ++s) {
    float wgt = wst[s];
    int r = src[s];
    uint4 v = *((const uint4*)(ycat + (size_t)r * 512) + lane);
#pragma unroll
    for (int q = 0; q < 4; ++q) {
      u32 word = ((const u32*)&v)[q];
      acc[2 * q]     += wgt * blo(word);
      acc[2 * q + 1] += wgt * bhi(word);
    }
  }
  float sw = dinv[node]; sw *= sw;
  uint4 v = *((const uint4*)(ycat + (size_t)node * 512) + lane);
#pragma unroll
  for (int q = 0; q < 4; ++q) {
    u32 word = ((const u32*)&v)[q];
    acc[2 * q]     += sw * blo(word);
    acc[2 * q + 1] += sw * bhi(word);
  }
  int f0 = lane * 8;
#pragma unroll
  for (int j = 0; j < 8; ++j) acc[j] += bcat[f0 + j];
  if (lane < 32) {
    float* o = zc + (size_t)node * 256 + f0;
    u16* ob = zcb + (size_t)node * 256 + f0;
#pragma unroll
    for (int j = 0; j < 8; ++j) { o[j] = acc[j]; ob[j] = f2b(acc[j]); }
  } else {
    float* o = zh + (size_t)node * 256 + (f0 - 256);
#pragma unroll
    for (int j = 0; j < 8; ++j) o[j] = acc[j];
  }
}

// ---------------- pooling helpers ----------------
__device__ inline int lbound(const int* a, int n, int v) {
  int lo = 0, hi = n;
  while (lo < hi) { int mid = (lo + hi) >> 1; if (a[mid] < v) lo = mid + 1; else hi = mid; }
  return lo;
}

#define POOL_NCH 32

__global__ __launch_bounds__(256) void k_poolpart2(const float* __restrict__ zc,
                                                   const float* __restrict__ zh,
                                                   const int* __restrict__ batch,
                                                   float* __restrict__ psum, float* __restrict__ pmax,
                                                   int n) {
  int g = blockIdx.x, yy = blockIdx.y;
  int half = (yy >= POOL_NCH) ? 1 : 0;
  int ch = yy - half * POOL_NCH;
  const float* z = half ? zh : zc;
  __shared__ int ss, se;
  if (threadIdx.x == 0) { ss = lbound(batch, n, g); se = lbound(batch, n, g + 1); }
  __syncthreads();
  int start = ss, len = se - ss;
  int c0 = start + (int)((long long)len * ch / POOL_NCH);
  int c1 = start + (int)((long long)len * (ch + 1) / POOL_NCH);
  int f = threadIdx.x;
  float acc = 0.0f, mx = -INFINITY;
  for (int i = c0; i < c1; ++i) {
    float v = z[(size_t)i * 256 + f];
    acc += v;
    mx = fmaxf(mx, v);
  }
  size_t o = ((size_t)(half * 64 + g) * POOL_NCH + ch) * 256 + f;
  psum[o] = acc;
  pmax[o] = mx;
}

// ---------------- fused: agg_dec (blocks < ab) + pool_final2 (rest) ----------------
__global__ __launch_bounds__(256) void k_finaldec(const u16* __restrict__ yd, float* __restrict__ xhat,
                                                  const int* __restrict__ rp, const int* __restrict__ src,
                                                  const float* __restrict__ wst, const float* __restrict__ dinv,
                                                  const float* __restrict__ bd, int n, int ab,
                                                  const float* __restrict__ psum, const float* __restrict__ pmax,
                                                  const int* __restrict__ batch,
                                                  float* __restrict__ z_g, float* __restrict__ zhat_g,
                                                  float* __restrict__ gcat) {
  if (blockIdx.x < ab) {
    int wv = threadIdx.x >> 6, lane = threadIdx.x & 63;
    int node = blockIdx.x * 4 + wv;
    if (node >= n) return;
    float a0 = 0.f, a1 = 0.f;
    int s0 = rp[node], s1 = rp[node + 1];
    int s = s0;
    for (; s + 8 <= s1; s += 8) {
      u32 v[8]; float wg[8];
#pragma unroll
      for (int u = 0; u < 8; ++u) {
        int r = src[s + u];
        wg[u] = wst[s + u];
        v[u] = *((const u32*)(yd + (size_t)r * 128) + lane);
      }
#pragma unroll
      for (int u = 0; u < 8; ++u) { a0 += wg[u] * blo(v[u]); a1 += wg[u] * bhi(v[u]); }
    }
    for (; s < s1; ++s) {
      float wgt = wst[s];
      int r = src[s];
      u32 w = *((const u32*)(yd + (size_t)r * 128) + lane);
      a0 += wgt * blo(w); a1 += wgt * bhi(w);
    }
    float sw = dinv[node]; sw *= sw;
    u32 w = *((const u32*)(yd + (size_t)node * 128) + lane);
    a0 += sw * blo(w); a1 += sw * bhi(w);
    float2 o;
    o.x = a0 + bd[lane * 2];
    o.y = a1 + bd[lane * 2 + 1];
    *((float2*)(xhat + (size_t)node * 128) + lane) = o;
    return;
  }
  int gg = blockIdx.x - ab, f = threadIdx.x;  // 0..127
  int g = gg & 63, half = gg >> 6;
  float s = 0.0f, m = -INFINITY;
#pragma unroll 4
  for (int c = 0; c < POOL_NCH; ++c) {
    size_t o = ((size_t)gg * POOL_NCH + c) * 256 + f;
    s += psum[o];
    m = fmaxf(m, pmax[o]);
  }
  __shared__ int ss, se;
  if (threadIdx.x == 0) { ss = lbound(batch, n, g); se = lbound(batch, n, g + 1); }
  __syncthreads();
  int cnt = se - ss;
  float mean = s / fmaxf((float)cnt, 1.0f);
  float mxo = (cnt > 0) ? m : 0.0f;
  float* zg = half ? zhat_g : z_g;
  zg[(size_t)g * 512 + f] = mean;
  zg[(size_t)g * 512 + 256 + f] = mxo;
  gcat[(size_t)gg * 512 + f] = mean;
  gcat[(size_t)gg * 512 + 256 + f] = mxo;
}

// ---------------- projection head: full 3-layer MLP, one block per row ----------------
__global__ __launch_bounds__(256) void k_proj(const float* __restrict__ gcat,
                                              const float* __restrict__ P1w, const float* __restrict__ P1b,
                                              const float* __restrict__ P2w, const float* __restrict__ P2b,
                                              const float* __restrict__ P3w, const float* __restrict__ P3b,
                                              float* __restrict__ outg) {
  __shared__ float gi[512];
  __shared__ float h1[256];
  __shared__ float h2[128];
  int r = blockIdx.x;  // 0..127
  int t = threadIdx.x;
  gi[t] = gcat[(size_t)r * 512 + t];
  gi[t + 256] = gcat[(size_t)r * 512 + 256 + t];
  __syncthreads();
  float a = 0.f;
#pragma unroll 8
  for (int k = 0; k < 512; ++k) a += gi[k] * P1w[k * 256 + t];
  h1[t] = fmaxf(a + P1b[t], 0.f);
  __syncthreads();
  if (t < 128) {
    float a2 = 0.f;
#pragma unroll 8
    for (int k = 0; k < 256; ++k) a2 += h1[k] * P2w[k * 128 + t];
    h2[t] = fmaxf(a2 + P2b[t], 0.f);
  }
  __syncthreads();
  if (t < 64) {
    float a3 = 0.f;
#pragma unroll 8
    for (int k = 0; k < 128; ++k) a3 += h2[k] * P3w[k * 64 + t];
    outg[(size_t)r * 64 + t] = a3 + P3b[t];
  }
}

// ---------------- launch ----------------
extern "C" void kernel_launch(void* const* d_in, const int* in_sizes, int n_in,
                              void* d_out, int out_size, void* d_ws, size_t ws_size,
                              hipStream_t stream) {
  const float* x   = (const float*)d_in[0];
  const int*   ei  = (const int*)d_in[1];
  const int*   bat = (const int*)d_in[2];
  const float* W1  = (const float*)d_in[4];
  const float* b1  = (const float*)d_in[5];
  const float* W2  = (const float*)d_in[6];
  const float* b2  = (const float*)d_in[7];
  const float* Wd  = (const float*)d_in[8];
  const float* bd  = (const float*)d_in[9];
  const float* P1w = (const float*)d_in[10];
  const float* P1b = (const float*)d_in[11];
  const float* P2w = (const float*)d_in[12];
  const float* P2b = (const float*)d_in[13];
  const float* P3w = (const float*)d_in[14];
  const float* P3b = (const float*)d_in[15];

  const int N = in_sizes[0] / 128;  // 50000
  const int E = in_sizes[1] / 2;    // 400000
  const int B = 64;
  const int NB = (N + 1023) / 1024;

  char* w = (char*)d_ws;
  auto carve = [&](size_t bytes) -> void* {
    void* p = (void*)w;
    w += (bytes + 255) & ~(size_t)255;
    return p;
  };
  int*    cnt        = (int*)carve((size_t)N * 4);
  int*    row_ptr    = (int*)carve((size_t)(N + 1) * 4);
  int*    cursor     = (int*)carve((size_t)N * 4);
  float*  dinv       = (float*)carve((size_t)N * 4);
  int*    incl       = (int*)carve((size_t)N * 4);
  int*    bsum       = (int*)carve((size_t)1024 * 4);
  int*    src_sorted = (int*)carve((size_t)E * 4);
  float*  w_sorted   = (float*)carve((size_t)E * 4);
  float*  sigma      = (float*)carve(256);
  double* psd        = (double*)carve((size_t)64 * 2 * 8);
  float*  b1h        = (float*)carve((size_t)512 * 4);
  float*  b2h        = (float*)carve((size_t)256 * 4);
  float*  bcat       = (float*)carve((size_t)512 * 4);
  u16*    W1T        = (u16*)carve((size_t)128 * 512 * 2);
  u16*    W2T        = (u16*)carve((size_t)512 * 256 * 2);
  u16*    WdT        = (u16*)carve((size_t)256 * 128 * 2);
  u16*    W1hT       = (u16*)carve((size_t)128 * 512 * 2);
  u16*    W2hT       = (u16*)carve((size_t)512 * 256 * 2);
  u16*    xb         = (u16*)carve((size_t)N * 128 * 2);
  u16*    px         = (u16*)carve((size_t)N * 128 * 2);
  u16*    z1c        = (u16*)carve((size_t)N * 512 * 2);   // clean L1 out
  u16*    z1p        = (u16*)carve((size_t)N * 512 * 2);   // pert L1 out
  u16*    ycat       = (u16*)carve((size_t)N * 512 * 2);   // [y_clean | y_pert]; later aliased yd
  u16*    znb        = (u16*)carve((size_t)N * 256 * 2);   // bf16 z_node (decoder A)
  float*  gcat       = (float*)carve((size_t)128 * 512 * 4);
  float*  psum       = (float*)carve((size_t)2 * B * POOL_NCH * 256 * 4);
  float*  pmax       = (float*)carve((size_t)2 * B * POOL_NCH * 256 * 4);
  u16*    yd         = ycat;  // alias: ycat dead after k_agg512

  float* out       = (float*)d_out;
  float* z_node    = out;
  float* z_g       = z_node + (size_t)N * 256;
  float* zhat_node = z_g + (size_t)B * 512;
  float* zhat_g    = zhat_node + (size_t)N * 256;
  float* h_g       = zhat_g + (size_t)B * 512;           // h_g||hhat_g contiguous
  float* x_hat     = h_g + (size_t)2 * B * 64;

  // nk = split(key(42), 4): nk[i] = threefry(key, (0, i))
  u32 nk[4][2];
  for (u32 i = 0; i < 4; ++i) tf2x32(0u, 42u, 0u, i, &nk[i][0], &nk[i][1]);

  const int c1 = (E + 255) / 256;
  const int n4b = (N * 128 / 4 + 255) / 256;
  const int prepABlocks = c1 + 64 + 256 + 512 + 128 + n4b;
  const int aggBlocks = (N + 3) / 4;
  const int MB = (N + 127) / 128;

  // 1-2: prep
  hipMemsetAsync(cnt, 0, (size_t)N * 4, stream);
  k_prepA<<<prepABlocks, 256, 0, stream>>>(ei, cnt, E, W1, b1, W2, b2, psd,
                                           Wd, W1T, W2T, WdT, x, xb, N, c1);
  // 3-6: CSR build
  k_scan_local<<<NB, 1024, 0, stream>>>(cnt, incl, bsum, N);
  k_small2<<<2, 256, 0, stream>>>(bsum, NB, psd, sigma);
  k_scan_final<<<NB, 1024, 0, stream>>>(cnt, incl, bsum, row_ptr, cursor, dinv, N, E);
  k_place<<<(E + 255) / 256, 256, 0, stream>>>(ei, cursor, dinv, src_sorted, w_sorted, E);

  // 7: perturb + agg_px fused
  k_pxper<<<771 + aggBlocks, 256, 0, stream>>>(W1, b1, W2, b2, W1hT, b1h, W2hT, b2h, bcat, sigma,
                                               nk[0][0], nk[0][1], nk[1][0], nk[1][1],
                                               nk[2][0], nk[2][1], nk[3][0], nk[3][1],
                                               xb, px, row_ptr, src_sorted, w_sorted, dinv, N);

  // 8: L1 both branches, A-resident column-loop
  k_mgemmL1<<<dim3(MB, 2), 256, 0, stream>>>(px, W1T, W1hT, b1, b1h, z1c, z1p, N);

  // 9: L2 both branches -> ycat [clean | pert], 2-phase double-buffered
  k_mgemm2<false, false><<<dim3(2, MB, 2), 256, 0, stream>>>(z1c, z1p, W2T, W2hT, nullptr, nullptr,
                                                             ycat, ycat, N, 512, 512, 0, 256);

  // 10: merged propagation
  k_agg512<<<aggBlocks, 256, 0, stream>>>(ycat, z_node, znb, zhat_node,
                                          row_ptr, src_sorted, w_sorted, dinv, bcat, N);

  // 11: decoder GEMM (2-phase double-buffered)
  k_mgemm1<<<MB, 256, 0, stream>>>(znb, WdT, yd, N);
  // 12: pool stage-1
  dim3 pgrid(B, 2 * POOL_NCH);
  k_poolpart2<<<pgrid, 256, 0, stream>>>(z_node, zhat_node, bat, psum, pmax, N);

  // 13: decoder propagation + pool stage-2
  k_finaldec<<<aggBlocks + 128, 256, 0, stream>>>(yd, x_hat, row_ptr, src_sorted, w_sorted, dinv, bd,
                                                  N, aggBlocks, psum, pmax, bat, z_g, zhat_g, gcat);

  // 14: projection heads
  k_proj<<<128, 256, 0, stream>>>(gcat, P1w, P1b, P2w, P2b, P3w, P3b, h_g);
}

// Round 15
// 412.701 us; speedup vs baseline: 1.1687x; 1.1687x over previous
//
#include <hip/hip_runtime.h>

typedef unsigned short u16;
typedef unsigned int u32;
typedef short bf16x8 __attribute__((ext_vector_type(8)));
typedef float f32x4 __attribute__((ext_vector_type(4)));

// ---------------- threefry2x32 (JAX-compatible, 20 rounds) ----------------
__host__ __device__ inline u32 rotl32(u32 x, int r) { return (x << r) | (x >> (32 - r)); }

__host__ __device__ inline void tf_r4(u32& x0, u32& x1, int r0, int r1, int r2, int r3) {
  x0 += x1; x1 = rotl32(x1, r0); x1 ^= x0;
  x0 += x1; x1 = rotl32(x1, r1); x1 ^= x0;
  x0 += x1; x1 = rotl32(x1, r2); x1 ^= x0;
  x0 += x1; x1 = rotl32(x1, r3); x1 ^= x0;
}

__host__ __device__ inline void tf2x32(u32 k0, u32 k1, u32 c0, u32 c1, u32* o0, u32* o1) {
  u32 ks2 = 0x1BD11BDAu ^ k0 ^ k1;
  u32 x0 = c0 + k0, x1 = c1 + k1;
  tf_r4(x0, x1, 13, 15, 26, 6);  x0 += k1;  x1 += ks2 + 1u;
  tf_r4(x0, x1, 17, 29, 16, 24); x0 += ks2; x1 += k0 + 2u;
  tf_r4(x0, x1, 13, 15, 26, 6);  x0 += k0;  x1 += k1 + 3u;
  tf_r4(x0, x1, 17, 29, 16, 24); x0 += k1;  x1 += ks2 + 4u;
  tf_r4(x0, x1, 13, 15, 26, 6);  x0 += ks2; x1 += k0 + 5u;
  *o0 = x0; *o1 = x1;
}

// XLA/Giles f32 erfinv
__device__ inline float erfinv_f(float x) {
  float w = -log1pf(-x * x);
  float p;
  if (w < 5.0f) {
    w -= 2.5f;
    p = 2.81022636e-08f;
    p = 3.43273939e-07f + p * w;
    p = -3.5233877e-06f + p * w;
    p = -4.39150654e-06f + p * w;
    p = 0.00021858087f + p * w;
    p = -0.00125372503f + p * w;
    p = -0.00417768164f + p * w;
    p = 0.246640727f + p * w;
    p = 1.50140941f + p * w;
  } else {
    w = sqrtf(w) - 3.0f;
    p = -0.000200214257f;
    p = 0.000100950558f + p * w;
    p = 0.00134934322f + p * w;
    p = -0.00367342844f + p * w;
    p = 0.00573950773f + p * w;
    p = -0.0076224613f + p * w;
    p = 0.00943887047f + p * w;
    p = 1.00167406f + p * w;
    p = 2.83297682f + p * w;
  }
  return p * x;
}

__device__ inline float bits2normal(u32 b) {
  float f = __uint_as_float((b >> 9) | 0x3F800000u) - 1.0f;  // [0,1)
  float u = f * 2.0f - 0.99999994f;
  u = fmaxf(u, -0.99999994f);
  return 1.41421356f * erfinv_f(u);
}

// ---------------- dtype helpers ----------------
__device__ inline void stor(u16* p, float v) {
  u32 x = __float_as_uint(v);
  *p = (u16)((x + 0x7FFFu + ((x >> 16) & 1u)) >> 16);  // RTNE bf16
}
__device__ inline u16 f2b(float v) {
  u32 x = __float_as_uint(v);
  return (u16)((x + 0x7FFFu + ((x >> 16) & 1u)) >> 16);
}
__device__ inline float blo(u32 w) { return __uint_as_float(w << 16); }
__device__ inline float bhi(u32 w) { return __uint_as_float(w & 0xFFFF0000u); }

// ---------------- fused prep A: count + std1 + clean transposes + x cast ----------------
__global__ __launch_bounds__(256) void k_prepA(const int* __restrict__ ei, int* __restrict__ cnt, int E,
                                               const float* __restrict__ W1, const float* __restrict__ b1,
                                               const float* __restrict__ W2, const float* __restrict__ b2,
                                               double* __restrict__ psd,
                                               const float* __restrict__ Wd,
                                               u16* __restrict__ W1T, u16* __restrict__ W2T, u16* __restrict__ WdT,
                                               const float* __restrict__ x, u16* __restrict__ xb,
                                               int N, int c1) {
  __shared__ double sh[256];
  __shared__ double sh2[256];
  int b = blockIdx.x;
  if (b < c1) {  // degree count
    int e = b * 256 + threadIdx.x;
    if (e < E) atomicAdd(&cnt[ei[E + e]], 1);
    return;
  }
  b -= c1;
  if (b < 64) {  // std1: 4 tensors x 16 chunks
    int t = b >> 4, ch = b & 15;
    const float* p; int n;
    if (t == 0) { p = W1; n = 128 * 512; }
    else if (t == 1) { p = b1; n = 512; }
    else if (t == 2) { p = W2; n = 512 * 256; }
    else { p = b2; n = 256; }
    int s0 = (int)((long long)n * ch / 16), s1 = (int)((long long)n * (ch + 1) / 16);
    double s = 0.0, ss = 0.0;
    for (int i = s0 + threadIdx.x; i < s1; i += 256) { double v = p[i]; s += v; ss += v * v; }
    sh[threadIdx.x] = s; sh2[threadIdx.x] = ss;
    __syncthreads();
    for (int o = 128; o > 0; o >>= 1) {
      if (threadIdx.x < o) { sh[threadIdx.x] += sh[threadIdx.x + o]; sh2[threadIdx.x] += sh2[threadIdx.x + o]; }
      __syncthreads();
    }
    if (threadIdx.x == 0) { psd[b * 2] = sh[0]; psd[b * 2 + 1] = sh2[0]; }
    return;
  }
  b -= 64;
  if (b < 256) {  // W1T: f32 [128][512] -> bf16 [512][128]
    int j = b * 256 + threadIdx.x;
    int k = j >> 9, n = j & 511;
    W1T[(size_t)n * 128 + k] = f2b(W1[j]);
    return;
  }
  b -= 256;
  if (b < 512) {  // W2T: [512][256] -> [256][512]
    int j = b * 256 + threadIdx.x;
    int k = j >> 8, n = j & 255;
    W2T[(size_t)n * 512 + k] = f2b(W2[j]);
    return;
  }
  b -= 512;
  if (b < 128) {  // WdT: [256][128] -> [128][256]
    int j = b * 256 + threadIdx.x;
    int k = j >> 7, n = j & 127;
    WdT[(size_t)n * 256 + k] = f2b(Wd[j]);
    return;
  }
  b -= 128;
  {  // xb cast: 4 f32 per thread
    int j = b * 256 + threadIdx.x;
    int n4 = N * 128 / 4;
    if (j < n4) {
      float4 v = ((const float4*)x)[j];
      ((u32*)xb)[j * 2] = ((u32)f2b(v.x)) | (((u32)f2b(v.y)) << 16);
      ((u32*)xb)[j * 2 + 1] = ((u32)f2b(v.z)) | (((u32)f2b(v.w)) << 16);
    }
  }
}

// ---------------- graph preprocessing ----------------
__global__ __launch_bounds__(1024) void k_scan_local(const int* __restrict__ cnt,
                                                     int* __restrict__ incl, int* __restrict__ bsum,
                                                     int n) {
  __shared__ int buf[1024];
  int i = blockIdx.x * 1024 + threadIdx.x;
  int v = (i < n) ? cnt[i] : 0;
  buf[threadIdx.x] = v;
  __syncthreads();
  for (int off = 1; off < 1024; off <<= 1) {
    int t = (threadIdx.x >= off) ? buf[threadIdx.x - off] : 0;
    __syncthreads();
    buf[threadIdx.x] += t;
    __syncthreads();
  }
  if (i < n) incl[i] = buf[threadIdx.x];
  if (threadIdx.x == 1023) bsum[blockIdx.x] = buf[1023];
}

// block 0: exclusive-scan bsum; block 1: std2 finalize
__global__ __launch_bounds__(256) void k_small2(int* __restrict__ bsum, int nb,
                                                const double* __restrict__ psd, float* __restrict__ sigma) {
  if (blockIdx.x == 0) {
    __shared__ int buf[256];
    int v = (threadIdx.x < nb) ? bsum[threadIdx.x] : 0;
    buf[threadIdx.x] = v;
    __syncthreads();
    for (int off = 1; off < 256; off <<= 1) {
      int t = (threadIdx.x >= off) ? buf[threadIdx.x - off] : 0;
      __syncthreads();
      buf[threadIdx.x] += t;
      __syncthreads();
    }
    if (threadIdx.x < nb) bsum[threadIdx.x] = buf[threadIdx.x] - v;  // exclusive
  } else {
    int l = threadIdx.x;
    if (l < 64) {
      double s = psd[l * 2], ss = psd[l * 2 + 1];
      for (int off = 1; off < 16; off <<= 1) { s += __shfl_xor(s, off); ss += __shfl_xor(ss, off); }
      if ((l & 15) == 0) {
        int t = l >> 4;
        int n = (t == 0) ? 128 * 512 : (t == 1) ? 512 : (t == 2) ? 512 * 256 : 256;
        double mean = s / n;
        double var = (ss - s * mean) / (double)(n - 1);
        if (var < 0.0) var = 0.0;
        sigma[t] = fmaxf((float)sqrt(var), 1e-6f);
      }
    }
  }
}

__global__ __launch_bounds__(1024) void k_scan_final(const int* __restrict__ cnt,
                                                     const int* __restrict__ incl,
                                                     const int* __restrict__ bsum,
                                                     int* __restrict__ row_ptr, int* __restrict__ cursor,
                                                     float* __restrict__ dinv, int n, int E) {
  int i = blockIdx.x * 1024 + threadIdx.x;
  if (i < n) {
    int c = cnt[i];
    int ex = incl[i] + bsum[blockIdx.x] - c;
    row_ptr[i] = ex;
    cursor[i] = ex;
    dinv[i] = 1.0f / sqrtf((float)(c + 1));  // deg includes self-loop
  }
  if (i == 0) row_ptr[n] = E;
}

__global__ void k_place(const int* __restrict__ ei, int* __restrict__ cursor,
                        const float* __restrict__ dinv, int* __restrict__ src_sorted,
                        float* __restrict__ w_sorted, int E) {
  int e = blockIdx.x * blockDim.x + threadIdx.x;
  if (e < E) {
    int s = ei[e], d = ei[E + e];
    int slot = atomicAdd(&cursor[d], 1);
    src_sorted[slot] = s;
    w_sorted[slot] = dinv[s] * dinv[d];
  }
}

// ---------------- fused: perturbAll (blocks 0..770) + agg_px (rest) ----------------
__global__ __launch_bounds__(256) void k_pxper(const float* __restrict__ W1, const float* __restrict__ b1,
                                               const float* __restrict__ W2, const float* __restrict__ b2,
                                               u16* __restrict__ W1hT, float* __restrict__ b1h,
                                               u16* __restrict__ W2hT, float* __restrict__ b2h,
                                               float* __restrict__ bcat,
                                               const float* __restrict__ sigma,
                                               u32 k00, u32 k01, u32 k10, u32 k11,
                                               u32 k20, u32 k21, u32 k30, u32 k31,
                                               const u16* __restrict__ xb, u16* __restrict__ px,
                                               const int* __restrict__ rp, const int* __restrict__ src,
                                               const float* __restrict__ wst, const float* __restrict__ dinv,
                                               int n) {
  int b = blockIdx.x;
  u32 r0, r1;
  if (b < 256) {  // W1 [128][512]
    int j = b * 256 + threadIdx.x;
    tf2x32(k00, k01, 0u, (u32)j, &r0, &r1);
    float v = W1[j] + sigma[0] * bits2normal(r0 ^ r1);
    int k = j >> 9, nn = j & 511;
    W1hT[(size_t)nn * 128 + k] = f2b(v);
    return;
  }
  b -= 256;
  if (b < 2) {  // b1 [512]
    int j = b * 256 + threadIdx.x;
    tf2x32(k10, k11, 0u, (u32)j, &r0, &r1);
    b1h[j] = b1[j] + sigma[1] * bits2normal(r0 ^ r1);
    return;
  }
  b -= 2;
  if (b < 512) {  // W2 [512][256]
    int j = b * 256 + threadIdx.x;
    tf2x32(k20, k21, 0u, (u32)j, &r0, &r1);
    float v = W2[j] + sigma[2] * bits2normal(r0 ^ r1);
    int k = j >> 8, nn = j & 255;
    W2hT[(size_t)nn * 512 + k] = f2b(v);
    return;
  }
  b -= 512;
  if (b < 1) {  // b2 [256] + bcat
    int j = threadIdx.x;
    tf2x32(k30, k31, 0u, (u32)j, &r0, &r1);
    float v = b2[j] + sigma[3] * bits2normal(r0 ^ r1);
    b2h[j] = v;
    bcat[256 + j] = v;
    bcat[j] = b2[j];
    return;
  }
  b -= 1;
  // ---- agg_px part ----
  int wv = threadIdx.x >> 6, lane = threadIdx.x & 63;
  int node = b * 4 + wv;
  if (node >= n) return;
  float a0 = 0.f, a1 = 0.f;
  int s0 = rp[node], s1 = rp[node + 1];
  int s = s0;
  for (; s + 8 <= s1; s += 8) {
    u32 v[8]; float wg[8];
#pragma unroll
    for (int u = 0; u < 8; ++u) {
      int r = src[s + u];
      wg[u] = wst[s + u];
      v[u] = *((const u32*)(xb + (size_t)r * 128) + lane);
    }
#pragma unroll
    for (int u = 0; u < 8; ++u) { a0 += wg[u] * blo(v[u]); a1 += wg[u] * bhi(v[u]); }
  }
  for (; s < s1; ++s) {
    float wgt = wst[s];
    int r = src[s];
    u32 w = *((const u32*)(xb + (size_t)r * 128) + lane);
    a0 += wgt * blo(w); a1 += wgt * bhi(w);
  }
  float sw = dinv[node]; sw *= sw;
  u32 w = *((const u32*)(xb + (size_t)node * 128) + lane);
  a0 += sw * blo(w); a1 += sw * bhi(w);
  u32 o = ((u32)f2b(a0)) | (((u32)f2b(a1)) << 16);
  *((u32*)(px + (size_t)node * 128) + lane) = o;
}

// ---------------- L1 GEMM: A-resident column-loop (unchanged) ----------------
__global__ __launch_bounds__(256) void k_mgemmL1(const u16* __restrict__ A,
                                                 const u16* __restrict__ BT0, const u16* __restrict__ BT1,
                                                 const float* __restrict__ bias0, const float* __restrict__ bias1,
                                                 u16* __restrict__ C0, u16* __restrict__ C1,
                                                 int M) {
  __shared__ u16 As[16384];
  __shared__ u16 Bs[16384];
  const u16* BT = blockIdx.y ? BT1 : BT0;
  const float* bias = blockIdx.y ? bias1 : bias0;
  u16* C = blockIdx.y ? C1 : C0;
  const int t = threadIdx.x;
  const int w = t >> 6, lane = t & 63;
  const int brow = blockIdx.x * 128;
  const int wr = w >> 1, wc = w & 1;

#pragma unroll
  for (int j = 0; j < 8; ++j) {
    int c = j * 4 + w;
    int lc = c * 64 + lane;
    int row = lc >> 4, ch = lc & 15;
    int chs = ch ^ (row & 15);
    int ar = brow + row; if (ar > M - 1) ar = M - 1;
    __builtin_amdgcn_global_load_lds(
        (const __attribute__((address_space(1))) void*)(A + (size_t)ar * 128 + chs * 8),
        (__attribute__((address_space(3))) void*)(As + c * 512), 16, 0, 0);
  }

  for (int cb = 0; cb < 4; ++cb) {
    int bcol = cb * 128;
#pragma unroll
    for (int j = 0; j < 8; ++j) {
      int c = j * 4 + w;
      int lc = c * 64 + lane;
      int row = lc >> 4, ch = lc & 15;
      int chs = ch ^ (row & 15);
      __builtin_amdgcn_global_load_lds(
          (const __attribute__((address_space(1))) void*)(BT + (size_t)(bcol + row) * 128 + chs * 8),
          (__attribute__((address_space(3))) void*)(Bs + c * 512), 16, 0, 0);
    }
    __syncthreads();

    f32x4 acc[4][4];
#pragma unroll
    for (int m = 0; m < 4; ++m)
#pragma unroll
      for (int n = 0; n < 4; ++n) acc[m][n] = (f32x4){0.f, 0.f, 0.f, 0.f};

#pragma unroll
    for (int kk = 0; kk < 4; ++kk) {
      int ch = kk * 4 + (lane >> 4);
      bf16x8 af[4], bb[4];
#pragma unroll
      for (int m = 0; m < 4; ++m) {
        int row = wr * 64 + m * 16 + (lane & 15);
        af[m] = *(const bf16x8*)(As + row * 128 + ((ch ^ (row & 15)) << 3));
      }
#pragma unroll
      for (int n = 0; n < 4; ++n) {
        int row = wc * 64 + n * 16 + (lane & 15);
        bb[n] = *(const bf16x8*)(Bs + row * 128 + ((ch ^ (row & 15)) << 3));
      }
#pragma unroll
      for (int m = 0; m < 4; ++m)
#pragma unroll
        for (int n = 0; n < 4; ++n)
          acc[m][n] = __builtin_amdgcn_mfma_f32_16x16x32_bf16(af[m], bb[n], acc[m][n], 0, 0, 0);
    }
    __syncthreads();

    u16* wlds = Bs + w * 4096;
#pragma unroll
    for (int m = 0; m < 4; ++m) {
      int lr0 = m * 16 + (lane >> 4) * 4;
#pragma unroll
      for (int n = 0; n < 4; ++n) {
        int lc = n * 16 + (lane & 15);
        float bv = bias[bcol + wc * 64 + lc];
        int chunk = lc >> 3, wi = lc & 7;
#pragma unroll
        for (int q = 0; q < 4; ++q) {
          int lr = lr0 + q;
          float v = fmaxf(acc[m][n][q] + bv, 0.0f);
          wlds[lr * 64 + ((chunk ^ (lr & 7)) << 3) + wi] = f2b(v);
        }
      }
    }
    int sr = lane >> 3, sc = lane & 7;
#pragma unroll
    for (int i = 0; i < 8; ++i) {
      int lr = i * 8 + sr;
      int gr = brow + wr * 64 + lr;
      if (gr < M) {
        uint4 vv = *(const uint4*)(wlds + lr * 64 + ((sc ^ (lr & 7)) << 3));
        *(uint4*)(C + (size_t)gr * 512 + bcol + wc * 64 + sc * 8) = vv;
      }
    }
    __syncthreads();
  }
}

// ---------------- MFMA tile body: 8-wave (512t), 64x32 wave-tiles, single-buffer ----------------
// Lower per-wave register footprint (acc 32 AGPR, frags 48 VGPR) -> more waves/SIMD
// to hide the K-step barrier drain. 128x128 block tile, BK=64, proven swizzle + staged epilogue.
template <bool RELU, bool BIAS>
__device__ inline void mgemm_tile8(u16* __restrict__ As, u16* __restrict__ Bs,
                                   const u16* __restrict__ A, const u16* __restrict__ BT,
                                   const float* __restrict__ bias, u16* __restrict__ C,
                                   int M, int K, int ldc, int coloff, int bx, int by) {
  const int t = threadIdx.x;           // 0..511
  const int w = t >> 6, lane = t & 63; // 8 waves
  const int brow = by * 128;
  const int bcol = bx * 128;
  const int wr = w >> 2, wc = w & 3;   // 2x4 wave grid: 64-row x 32-col tiles

  f32x4 acc[4][2];
#pragma unroll
  for (int m = 0; m < 4; ++m)
#pragma unroll
    for (int n = 0; n < 2; ++n) acc[m][n] = (f32x4){0.f, 0.f, 0.f, 0.f};

  for (int kt = 0; kt < K; kt += 64) {
#pragma unroll
    for (int j = 0; j < 2; ++j) {
      int c = j * 8 + w;              // chunk group 0..15 (wave-uniform)
      int li = c * 64 + lane;         // 16B unit index 0..1023
      int row = li >> 3, col8 = li & 7;
      int col8s = col8 ^ (row & 7);   // source swizzle
      int ar = brow + row; if (ar > M - 1) ar = M - 1;
      __builtin_amdgcn_global_load_lds(
          (const __attribute__((address_space(1))) void*)(A + (size_t)ar * K + kt + col8s * 8),
          (__attribute__((address_space(3))) void*)(As + c * 512), 16, 0, 0);
      __builtin_amdgcn_global_load_lds(
          (const __attribute__((address_space(1))) void*)(BT + (size_t)(bcol + row) * K + kt + col8s * 8),
          (__attribute__((address_space(3))) void*)(Bs + c * 512), 16, 0, 0);
    }
    __syncthreads();
    bf16x8 af[4][2], bb[2][2];
#pragma unroll
    for (int kk = 0; kk < 2; ++kk) {
      int ch = kk * 4 + (lane >> 4);
      int chs = ch ^ (lane & 7);
#pragma unroll
      for (int m = 0; m < 4; ++m)
        af[m][kk] = *(const bf16x8*)(As + (wr * 64 + m * 16 + (lane & 15)) * 64 + chs * 8);
#pragma unroll
      for (int n = 0; n < 2; ++n)
        bb[n][kk] = *(const bf16x8*)(Bs + (wc * 32 + n * 16 + (lane & 15)) * 64 + chs * 8);
    }
#pragma unroll
    for (int kk = 0; kk < 2; ++kk)
#pragma unroll
      for (int m = 0; m < 4; ++m)
#pragma unroll
        for (int n = 0; n < 2; ++n)
          acc[m][n] = __builtin_amdgcn_mfma_f32_16x16x32_bf16(af[m][kk], bb[n][kk], acc[m][n], 0, 0, 0);
    __syncthreads();
  }

  // epilogue: per-wave 64x32 bf16 scratch (4KB) in As/Bs regions, then coalesced stores
  u16* wlds = ((w & 4) ? Bs : As) + (w & 3) * 2048;
#pragma unroll
  for (int m = 0; m < 4; ++m) {
    int lr0 = m * 16 + (lane >> 4) * 4;
#pragma unroll
    for (int n = 0; n < 2; ++n) {
      int lc = n * 16 + (lane & 15);
      float bv = BIAS ? bias[bcol + wc * 32 + lc] : 0.0f;
      int chunk = lc >> 3, wi = lc & 7;
#pragma unroll
      for (int q = 0; q < 4; ++q) {
        int lr = lr0 + q;
        float v = acc[m][n][q] + bv;
        if (RELU) v = fmaxf(v, 0.0f);
        wlds[lr * 32 + ((chunk ^ (lr & 3)) << 3) + wi] = f2b(v);
      }
    }
  }
  // coalesced stores: each lane row lr = i*16 + (lane>>2), chunk sc = lane&3
  int sc = lane & 3;
#pragma unroll
  for (int i = 0; i < 4; ++i) {
    int lr = i * 16 + (lane >> 2);
    int gr = brow + wr * 64 + lr;
    if (gr < M) {
      uint4 vv = *(const uint4*)(wlds + lr * 32 + ((sc ^ (lr & 3)) << 3));
      *(uint4*)(C + (size_t)gr * ldc + coloff + bcol + wc * 32 + sc * 8) = vv;
    }
  }
}

// dual-branch GEMM (L2): blockIdx.z selects branch; 512 threads
template <bool RELU, bool BIAS>
__global__ __launch_bounds__(512) void k_mgemm2(const u16* A0, const u16* A1,
                                                const u16* BT0, const u16* BT1,
                                                const float* bias0, const float* bias1,
                                                u16* C0, u16* C1,
                                                int M, int K, int ldc, int co0, int co1) {
  __shared__ u16 As[8192];
  __shared__ u16 Bs[8192];
  int z = blockIdx.z;
  mgemm_tile8<RELU, BIAS>(As, Bs, z ? A1 : A0, z ? BT1 : BT0, z ? bias1 : bias0,
                          z ? C1 : C0, M, K, ldc, z ? co1 : co0, blockIdx.x, blockIdx.y);
}

// single-branch GEMM (decoder); 512 threads
__global__ __launch_bounds__(512) void k_mgemm1(const u16* __restrict__ A, const u16* __restrict__ BT,
                                                u16* __restrict__ C, int M) {
  __shared__ u16 As[8192];
  __shared__ u16 Bs[8192];
  mgemm_tile8<false, false>(As, Bs, A, BT, nullptr, C, M, 256, 128, 0, 0, blockIdx.x);
}

// ---------------- merged layer-2 agg (4-deep unroll) ----------------
__global__ __launch_bounds__(256) void k_agg512(const u16* __restrict__ ycat,
                                                float* __restrict__ zc, u16* __restrict__ zcb,
                                                float* __restrict__ zh,
                                                const int* __restrict__ rp, const int* __restrict__ src,
                                                const float* __restrict__ wst, const float* __restrict__ dinv,
                                                const float* __restrict__ bcat, int n) {
  int wv = threadIdx.x >> 6, lane = threadIdx.x & 63;
  int node = blockIdx.x * 4 + wv;
  if (node >= n) return;
  float acc[8] = {};
  int s0 = rp[node], s1 = rp[node + 1];
  int s = s0;
  for (; s + 4 <= s1; s += 4) {
    uint4 v[4]; float wg[4];
#pragma unroll
    for (int u = 0; u < 4; ++u) {
      int r = src[s + u];
      wg[u] = wst[s + u];
      v[u] = *((const uint4*)(ycat + (size_t)r * 512) + lane);
    }
#pragma unroll
    for (int u = 0; u < 4; ++u)
#pragma unroll
      for (int q = 0; q < 4; ++q) {
        u32 word = ((const u32*)&v[u])[q];
        acc[2 * q]     += wg[u] * blo(word);
        acc[2 * q + 1] += wg[u] * bhi(word);
      }
  }
  for (; s < s1; ++s) {
    float wgt = wst[s];
    int r = src[s];
    uint4 v = *((const uint4*)(ycat + (size_t)r * 512) + lane);
#pragma unroll
    for (int q = 0; q < 4; ++q) {
      u32 word = ((const u32*)&v)[q];
      acc[2 * q]     += wgt * blo(word);
      acc[2 * q + 1] += wgt * bhi(word);
    }
  }
  float sw = dinv[node]; sw *= sw;
  uint4 v = *((const uint4*)(ycat + (size_t)node * 512) + lane);
#pragma unroll
  for (int q = 0; q < 4; ++q) {
    u32 word = ((const u32*)&v)[q];
    acc[2 * q]     += sw * blo(word);
    acc[2 * q + 1] += sw * bhi(word);
  }
  int f0 = lane * 8;
#pragma unroll
  for (int j = 0; j < 8; ++j) acc[j] += bcat[f0 + j];
  if (lane < 32) {
    float* o = zc + (size_t)node * 256 + f0;
    u16* ob = zcb + (size_t)node * 256 + f0;
#pragma unroll
    for (int j = 0; j < 8; ++j) { o[j] = acc[j]; ob[j] = f2b(acc[j]); }
  } else {
    float* o = zh + (size_t)node * 256 + (f0 - 256);
#pragma unroll
    for (int j = 0; j < 8; ++j) o[j] = acc[j];
  }
}

// ---------------- pooling helpers ----------------
__device__ inline int lbound(const int* a, int n, int v) {
  int lo = 0, hi = n;
  while (lo < hi) { int mid = (lo + hi) >> 1; if (a[mid] < v) lo = mid + 1; else hi = mid; }
  return lo;
}

#define POOL_NCH 32

__global__ __launch_bounds__(256) void k_poolpart2(const float* __restrict__ zc,
                                                   const float* __restrict__ zh,
                                                   const int* __restrict__ batch,
                                                   float* __restrict__ psum, float* __restrict__ pmax,
                                                   int n) {
  int g = blockIdx.x, yy = blockIdx.y;
  int half = (yy >= POOL_NCH) ? 1 : 0;
  int ch = yy - half * POOL_NCH;
  const float* z = half ? zh : zc;
  __shared__ int ss, se;
  if (threadIdx.x == 0) { ss = lbound(batch, n, g); se = lbound(batch, n, g + 1); }
  __syncthreads();
  int start = ss, len = se - ss;
  int c0 = start + (int)((long long)len * ch / POOL_NCH);
  int c1 = start + (int)((long long)len * (ch + 1) / POOL_NCH);
  int f = threadIdx.x;
  float acc = 0.0f, mx = -INFINITY;
  for (int i = c0; i < c1; ++i) {
    float v = z[(size_t)i * 256 + f];
    acc += v;
    mx = fmaxf(mx, v);
  }
  size_t o = ((size_t)(half * 64 + g) * POOL_NCH + ch) * 256 + f;
  psum[o] = acc;
  pmax[o] = mx;
}

// ---------------- fused: agg_dec (blocks < ab) + pool_final2 (rest) ----------------
__global__ __launch_bounds__(256) void k_finaldec(const u16* __restrict__ yd, float* __restrict__ xhat,
                                                  const int* __restrict__ rp, const int* __restrict__ src,
                                                  const float* __restrict__ wst, const float* __restrict__ dinv,
                                                  const float* __restrict__ bd, int n, int ab,
                                                  const float* __restrict__ psum, const float* __restrict__ pmax,
                                                  const int* __restrict__ batch,
                                                  float* __restrict__ z_g, float* __restrict__ zhat_g,
                                                  float* __restrict__ gcat) {
  if (blockIdx.x < ab) {
    int wv = threadIdx.x >> 6, lane = threadIdx.x & 63;
    int node = blockIdx.x * 4 + wv;
    if (node >= n) return;
    float a0 = 0.f, a1 = 0.f;
    int s0 = rp[node], s1 = rp[node + 1];
    int s = s0;
    for (; s + 8 <= s1; s += 8) {
      u32 v[8]; float wg[8];
#pragma unroll
      for (int u = 0; u < 8; ++u) {
        int r = src[s + u];
        wg[u] = wst[s + u];
        v[u] = *((const u32*)(yd + (size_t)r * 128) + lane);
      }
#pragma unroll
      for (int u = 0; u < 8; ++u) { a0 += wg[u] * blo(v[u]); a1 += wg[u] * bhi(v[u]); }
    }
    for (; s < s1; ++s) {
      float wgt = wst[s];
      int r = src[s];
      u32 w = *((const u32*)(yd + (size_t)r * 128) + lane);
      a0 += wgt * blo(w); a1 += wgt * bhi(w);
    }
    float sw = dinv[node]; sw *= sw;
    u32 w = *((const u32*)(yd + (size_t)node * 128) + lane);
    a0 += sw * blo(w); a1 += sw * bhi(w);
    float2 o;
    o.x = a0 + bd[lane * 2];
    o.y = a1 + bd[lane * 2 + 1];
    *((float2*)(xhat + (size_t)node * 128) + lane) = o;
    return;
  }
  int gg = blockIdx.x - ab, f = threadIdx.x;  // 0..127
  int g = gg & 63, half = gg >> 6;
  float s = 0.0f, m = -INFINITY;
#pragma unroll 4
  for (int c = 0; c < POOL_NCH; ++c) {
    size_t o = ((size_t)gg * POOL_NCH + c) * 256 + f;
    s += psum[o];
    m = fmaxf(m, pmax[o]);
  }
  __shared__ int ss, se;
  if (threadIdx.x == 0) { ss = lbound(batch, n, g); se = lbound(batch, n, g + 1); }
  __syncthreads();
  int cnt = se - ss;
  float mean = s / fmaxf((float)cnt, 1.0f);
  float mxo = (cnt > 0) ? m : 0.0f;
  float* zg = half ? zhat_g : z_g;
  zg[(size_t)g * 512 + f] = mean;
  zg[(size_t)g * 512 + 256 + f] = mxo;
  gcat[(size_t)gg * 512 + f] = mean;
  gcat[(size_t)gg * 512 + 256 + f] = mxo;
}

// ---------------- projection head: full 3-layer MLP, one block per row ----------------
__global__ __launch_bounds__(256) void k_proj(const float* __restrict__ gcat,
                                              const float* __restrict__ P1w, const float* __restrict__ P1b,
                                              const float* __restrict__ P2w, const float* __restrict__ P2b,
                                              const float* __restrict__ P3w, const float* __restrict__ P3b,
                                              float* __restrict__ outg) {
  __shared__ float gi[512];
  __shared__ float h1[256];
  __shared__ float h2[128];
  int r = blockIdx.x;  // 0..127
  int t = threadIdx.x;
  gi[t] = gcat[(size_t)r * 512 + t];
  gi[t + 256] = gcat[(size_t)r * 512 + 256 + t];
  __syncthreads();
  float a = 0.f;
#pragma unroll 8
  for (int k = 0; k < 512; ++k) a += gi[k] * P1w[k * 256 + t];
  h1[t] = fmaxf(a + P1b[t], 0.f);
  __syncthreads();
  if (t < 128) {
    float a2 = 0.f;
#pragma unroll 8
    for (int k = 0; k < 256; ++k) a2 += h1[k] * P2w[k * 128 + t];
    h2[t] = fmaxf(a2 + P2b[t], 0.f);
  }
  __syncthreads();
  if (t < 64) {
    float a3 = 0.f;
#pragma unroll 8
    for (int k = 0; k < 128; ++k) a3 += h2[k] * P3w[k * 64 + t];
    outg[(size_t)r * 64 + t] = a3 + P3b[t];
  }
}

// ---------------- launch ----------------
extern "C" void kernel_launch(void* const* d_in, const int* in_sizes, int n_in,
                              void* d_out, int out_size, void* d_ws, size_t ws_size,
                              hipStream_t stream) {
  const float* x   = (const float*)d_in[0];
  const int*   ei  = (const int*)d_in[1];
  const int*   bat = (const int*)d_in[2];
  const float* W1  = (const float*)d_in[4];
  const float* b1  = (const float*)d_in[5];
  const float* W2  = (const float*)d_in[6];
  const float* b2  = (const float*)d_in[7];
  const float* Wd  = (const float*)d_in[8];
  const float* bd  = (const float*)d_in[9];
  const float* P1w = (const float*)d_in[10];
  const float* P1b = (const float*)d_in[11];
  const float* P2w = (const float*)d_in[12];
  const float* P2b = (const float*)d_in[13];
  const float* P3w = (const float*)d_in[14];
  const float* P3b = (const float*)d_in[15];

  const int N = in_sizes[0] / 128;  // 50000
  const int E = in_sizes[1] / 2;    // 400000
  const int B = 64;
  const int NB = (N + 1023) / 1024;

  char* w = (char*)d_ws;
  auto carve = [&](size_t bytes) -> void* {
    void* p = (void*)w;
    w += (bytes + 255) & ~(size_t)255;
    return p;
  };
  int*    cnt        = (int*)carve((size_t)N * 4);
  int*    row_ptr    = (int*)carve((size_t)(N + 1) * 4);
  int*    cursor     = (int*)carve((size_t)N * 4);
  float*  dinv       = (float*)carve((size_t)N * 4);
  int*    incl       = (int*)carve((size_t)N * 4);
  int*    bsum       = (int*)carve((size_t)1024 * 4);
  int*    src_sorted = (int*)carve((size_t)E * 4);
  float*  w_sorted   = (float*)carve((size_t)E * 4);
  float*  sigma      = (float*)carve(256);
  double* psd        = (double*)carve((size_t)64 * 2 * 8);
  float*  b1h        = (float*)carve((size_t)512 * 4);
  float*  b2h        = (float*)carve((size_t)256 * 4);
  float*  bcat       = (float*)carve((size_t)512 * 4);
  u16*    W1T        = (u16*)carve((size_t)128 * 512 * 2);
  u16*    W2T        = (u16*)carve((size_t)512 * 256 * 2);
  u16*    WdT        = (u16*)carve((size_t)256 * 128 * 2);
  u16*    W1hT       = (u16*)carve((size_t)128 * 512 * 2);
  u16*    W2hT       = (u16*)carve((size_t)512 * 256 * 2);
  u16*    xb         = (u16*)carve((size_t)N * 128 * 2);
  u16*    px         = (u16*)carve((size_t)N * 128 * 2);
  u16*    z1c        = (u16*)carve((size_t)N * 512 * 2);   // clean L1 out
  u16*    z1p        = (u16*)carve((size_t)N * 512 * 2);   // pert L1 out
  u16*    ycat       = (u16*)carve((size_t)N * 512 * 2);   // [y_clean | y_pert]; later aliased yd
  u16*    znb        = (u16*)carve((size_t)N * 256 * 2);   // bf16 z_node (decoder A)
  float*  gcat       = (float*)carve((size_t)128 * 512 * 4);
  float*  psum       = (float*)carve((size_t)2 * B * POOL_NCH * 256 * 4);
  float*  pmax       = (float*)carve((size_t)2 * B * POOL_NCH * 256 * 4);
  u16*    yd         = ycat;  // alias: ycat dead after k_agg512

  float* out       = (float*)d_out;
  float* z_node    = out;
  float* z_g       = z_node + (size_t)N * 256;
  float* zhat_node = z_g + (size_t)B * 512;
  float* zhat_g    = zhat_node + (size_t)N * 256;
  float* h_g       = zhat_g + (size_t)B * 512;           // h_g||hhat_g contiguous
  float* x_hat     = h_g + (size_t)2 * B * 64;

  // nk = split(key(42), 4): nk[i] = threefry(key, (0, i))
  u32 nk[4][2];
  for (u32 i = 0; i < 4; ++i) tf2x32(0u, 42u, 0u, i, &nk[i][0], &nk[i][1]);

  const int c1 = (E + 255) / 256;
  const int n4b = (N * 128 / 4 + 255) / 256;
  const int prepABlocks = c1 + 64 + 256 + 512 + 128 + n4b;
  const int aggBlocks = (N + 3) / 4;
  const int MB = (N + 127) / 128;

  // 1-2: prep
  hipMemsetAsync(cnt, 0, (size_t)N * 4, stream);
  k_prepA<<<prepABlocks, 256, 0, stream>>>(ei, cnt, E, W1, b1, W2, b2, psd,
                                           Wd, W1T, W2T, WdT, x, xb, N, c1);
  // 3-6: CSR build
  k_scan_local<<<NB, 1024, 0, stream>>>(cnt, incl, bsum, N);
  k_small2<<<2, 256, 0, stream>>>(bsum, NB, psd, sigma);
  k_scan_final<<<NB, 1024, 0, stream>>>(cnt, incl, bsum, row_ptr, cursor, dinv, N, E);
  k_place<<<(E + 255) / 256, 256, 0, stream>>>(ei, cursor, dinv, src_sorted, w_sorted, E);

  // 7: perturb + agg_px fused
  k_pxper<<<771 + aggBlocks, 256, 0, stream>>>(W1, b1, W2, b2, W1hT, b1h, W2hT, b2h, bcat, sigma,
                                               nk[0][0], nk[0][1], nk[1][0], nk[1][1],
                                               nk[2][0], nk[2][1], nk[3][0], nk[3][1],
                                               xb, px, row_ptr, src_sorted, w_sorted, dinv, N);

  // 8: L1 both branches, A-resident column-loop
  k_mgemmL1<<<dim3(MB, 2), 256, 0, stream>>>(px, W1T, W1hT, b1, b1h, z1c, z1p, N);

  // 9: L2 both branches -> ycat [clean | pert], 8-wave low-pressure tiles
  k_mgemm2<false, false><<<dim3(2, MB, 2), 512, 0, stream>>>(z1c, z1p, W2T, W2hT, nullptr, nullptr,
                                                             ycat, ycat, N, 512, 512, 0, 256);

  // 10: merged propagation
  k_agg512<<<aggBlocks, 256, 0, stream>>>(ycat, z_node, znb, zhat_node,
                                          row_ptr, src_sorted, w_sorted, dinv, bcat, N);

  // 11: decoder GEMM (8-wave)
  k_mgemm1<<<MB, 512, 0, stream>>>(znb, WdT, yd, N);
  // 12: pool stage-1
  dim3 pgrid(B, 2 * POOL_NCH);
  k_poolpart2<<<pgrid, 256, 0, stream>>>(z_node, zhat_node, bat, psum, pmax, N);

  // 13: decoder propagation + pool stage-2
  k_finaldec<<<aggBlocks + 128, 256, 0, stream>>>(yd, x_hat, row_ptr, src_sorted, w_sorted, dinv, bd,
                                                  N, aggBlocks, psum, pmax, bat, z_g, zhat_g, gcat);

  // 14: projection heads
  k_proj<<<128, 256, 0, stream>>>(gcat, P1w, P1b, P2w, P2b, P3w, P3b, h_g);
}

// Round 16
// 406.037 us; speedup vs baseline: 1.1879x; 1.0164x over previous
//
#include <hip/hip_runtime.h>

typedef unsigned short u16;
typedef unsigned int u32;
typedef short bf16x8 __attribute__((ext_vector_type(8)));
typedef float f32x4 __attribute__((ext_vector_type(4)));

// ---------------- threefry2x32 (JAX-compatible, 20 rounds) ----------------
__host__ __device__ inline u32 rotl32(u32 x, int r) { return (x << r) | (x >> (32 - r)); }

__host__ __device__ inline void tf_r4(u32& x0, u32& x1, int r0, int r1, int r2, int r3) {
  x0 += x1; x1 = rotl32(x1, r0); x1 ^= x0;
  x0 += x1; x1 = rotl32(x1, r1); x1 ^= x0;
  x0 += x1; x1 = rotl32(x1, r2); x1 ^= x0;
  x0 += x1; x1 = rotl32(x1, r3); x1 ^= x0;
}

__host__ __device__ inline void tf2x32(u32 k0, u32 k1, u32 c0, u32 c1, u32* o0, u32* o1) {
  u32 ks2 = 0x1BD11BDAu ^ k0 ^ k1;
  u32 x0 = c0 + k0, x1 = c1 + k1;
  tf_r4(x0, x1, 13, 15, 26, 6);  x0 += k1;  x1 += ks2 + 1u;
  tf_r4(x0, x1, 17, 29, 16, 24); x0 += ks2; x1 += k0 + 2u;
  tf_r4(x0, x1, 13, 15, 26, 6);  x0 += k0;  x1 += k1 + 3u;
  tf_r4(x0, x1, 17, 29, 16, 24); x0 += k1;  x1 += ks2 + 4u;
  tf_r4(x0, x1, 13, 15, 26, 6);  x0 += ks2; x1 += k0 + 5u;
  *o0 = x0; *o1 = x1;
}

// XLA/Giles f32 erfinv
__device__ inline float erfinv_f(float x) {
  float w = -log1pf(-x * x);
  float p;
  if (w < 5.0f) {
    w -= 2.5f;
    p = 2.81022636e-08f;
    p = 3.43273939e-07f + p * w;
    p = -3.5233877e-06f + p * w;
    p = -4.39150654e-06f + p * w;
    p = 0.00021858087f + p * w;
    p = -0.00125372503f + p * w;
    p = -0.00417768164f + p * w;
    p = 0.246640727f + p * w;
    p = 1.50140941f + p * w;
  } else {
    w = sqrtf(w) - 3.0f;
    p = -0.000200214257f;
    p = 0.000100950558f + p * w;
    p = 0.00134934322f + p * w;
    p = -0.00367342844f + p * w;
    p = 0.00573950773f + p * w;
    p = -0.0076224613f + p * w;
    p = 0.00943887047f + p * w;
    p = 1.00167406f + p * w;
    p = 2.83297682f + p * w;
  }
  return p * x;
}

__device__ inline float bits2normal(u32 b) {
  float f = __uint_as_float((b >> 9) | 0x3F800000u) - 1.0f;  // [0,1)
  float u = f * 2.0f - 0.99999994f;
  u = fmaxf(u, -0.99999994f);
  return 1.41421356f * erfinv_f(u);
}

// ---------------- dtype helpers ----------------
__device__ inline void stor(u16* p, float v) {
  u32 x = __float_as_uint(v);
  *p = (u16)((x + 0x7FFFu + ((x >> 16) & 1u)) >> 16);  // RTNE bf16
}
__device__ inline u16 f2b(float v) {
  u32 x = __float_as_uint(v);
  return (u16)((x + 0x7FFFu + ((x >> 16) & 1u)) >> 16);
}
__device__ inline float blo(u32 w) { return __uint_as_float(w << 16); }
__device__ inline float bhi(u32 w) { return __uint_as_float(w & 0xFFFF0000u); }

// ---------------- fused prep A: count + std1 + clean transposes + x cast ----------------
__global__ __launch_bounds__(256) void k_prepA(const int* __restrict__ ei, int* __restrict__ cnt, int E,
                                               const float* __restrict__ W1, const float* __restrict__ b1,
                                               const float* __restrict__ W2, const float* __restrict__ b2,
                                               double* __restrict__ psd,
                                               const float* __restrict__ Wd,
                                               u16* __restrict__ W1T, u16* __restrict__ W2T, u16* __restrict__ WdT,
                                               const float* __restrict__ x, u16* __restrict__ xb,
                                               int N, int c1) {
  __shared__ double sh[256];
  __shared__ double sh2[256];
  int b = blockIdx.x;
  if (b < c1) {  // degree count
    int e = b * 256 + threadIdx.x;
    if (e < E) atomicAdd(&cnt[ei[E + e]], 1);
    return;
  }
  b -= c1;
  if (b < 64) {  // std1: 4 tensors x 16 chunks
    int t = b >> 4, ch = b & 15;
    const float* p; int n;
    if (t == 0) { p = W1; n = 128 * 512; }
    else if (t == 1) { p = b1; n = 512; }
    else if (t == 2) { p = W2; n = 512 * 256; }
    else { p = b2; n = 256; }
    int s0 = (int)((long long)n * ch / 16), s1 = (int)((long long)n * (ch + 1) / 16);
    double s = 0.0, ss = 0.0;
    for (int i = s0 + threadIdx.x; i < s1; i += 256) { double v = p[i]; s += v; ss += v * v; }
    sh[threadIdx.x] = s; sh2[threadIdx.x] = ss;
    __syncthreads();
    for (int o = 128; o > 0; o >>= 1) {
      if (threadIdx.x < o) { sh[threadIdx.x] += sh[threadIdx.x + o]; sh2[threadIdx.x] += sh2[threadIdx.x + o]; }
      __syncthreads();
    }
    if (threadIdx.x == 0) { psd[b * 2] = sh[0]; psd[b * 2 + 1] = sh2[0]; }
    return;
  }
  b -= 64;
  if (b < 256) {  // W1T: f32 [128][512] -> bf16 [512][128]
    int j = b * 256 + threadIdx.x;
    int k = j >> 9, n = j & 511;
    W1T[(size_t)n * 128 + k] = f2b(W1[j]);
    return;
  }
  b -= 256;
  if (b < 512) {  // W2T: [512][256] -> [256][512]
    int j = b * 256 + threadIdx.x;
    int k = j >> 8, n = j & 255;
    W2T[(size_t)n * 512 + k] = f2b(W2[j]);
    return;
  }
  b -= 512;
  if (b < 128) {  // WdT: [256][128] -> [128][256]
    int j = b * 256 + threadIdx.x;
    int k = j >> 7, n = j & 127;
    WdT[(size_t)n * 256 + k] = f2b(Wd[j]);
    return;
  }
  b -= 128;
  {  // xb cast: 4 f32 per thread
    int j = b * 256 + threadIdx.x;
    int n4 = N * 128 / 4;
    if (j < n4) {
      float4 v = ((const float4*)x)[j];
      ((u32*)xb)[j * 2] = ((u32)f2b(v.x)) | (((u32)f2b(v.y)) << 16);
      ((u32*)xb)[j * 2 + 1] = ((u32)f2b(v.z)) | (((u32)f2b(v.w)) << 16);
    }
  }
}

// ---------------- graph preprocessing ----------------
__global__ __launch_bounds__(1024) void k_scan_local(const int* __restrict__ cnt,
                                                     int* __restrict__ incl, int* __restrict__ bsum,
                                                     int n) {
  __shared__ int buf[1024];
  int i = blockIdx.x * 1024 + threadIdx.x;
  int v = (i < n) ? cnt[i] : 0;
  buf[threadIdx.x] = v;
  __syncthreads();
  for (int off = 1; off < 1024; off <<= 1) {
    int t = (threadIdx.x >= off) ? buf[threadIdx.x - off] : 0;
    __syncthreads();
    buf[threadIdx.x] += t;
    __syncthreads();
  }
  if (i < n) incl[i] = buf[threadIdx.x];
  if (threadIdx.x == 1023) bsum[blockIdx.x] = buf[1023];
}

// block 0: exclusive-scan bsum; block 1: std2 finalize
__global__ __launch_bounds__(256) void k_small2(int* __restrict__ bsum, int nb,
                                                const double* __restrict__ psd, float* __restrict__ sigma) {
  if (blockIdx.x == 0) {
    __shared__ int buf[256];
    int v = (threadIdx.x < nb) ? bsum[threadIdx.x] : 0;
    buf[threadIdx.x] = v;
    __syncthreads();
    for (int off = 1; off < 256; off <<= 1) {
      int t = (threadIdx.x >= off) ? buf[threadIdx.x - off] : 0;
      __syncthreads();
      buf[threadIdx.x] += t;
      __syncthreads();
    }
    if (threadIdx.x < nb) bsum[threadIdx.x] = buf[threadIdx.x] - v;  // exclusive
  } else {
    int l = threadIdx.x;
    if (l < 64) {
      double s = psd[l * 2], ss = psd[l * 2 + 1];
      for (int off = 1; off < 16; off <<= 1) { s += __shfl_xor(s, off); ss += __shfl_xor(ss, off); }
      if ((l & 15) == 0) {
        int t = l >> 4;
        int n = (t == 0) ? 128 * 512 : (t == 1) ? 512 : (t == 2) ? 512 * 256 : 256;
        double mean = s / n;
        double var = (ss - s * mean) / (double)(n - 1);
        if (var < 0.0) var = 0.0;
        sigma[t] = fmaxf((float)sqrt(var), 1e-6f);
      }
    }
  }
}

__global__ __launch_bounds__(1024) void k_scan_final(const int* __restrict__ cnt,
                                                     const int* __restrict__ incl,
                                                     const int* __restrict__ bsum,
                                                     int* __restrict__ row_ptr, int* __restrict__ cursor,
                                                     float* __restrict__ dinv, int n, int E) {
  int i = blockIdx.x * 1024 + threadIdx.x;
  if (i < n) {
    int c = cnt[i];
    int ex = incl[i] + bsum[blockIdx.x] - c;
    row_ptr[i] = ex;
    cursor[i] = ex;
    dinv[i] = 1.0f / sqrtf((float)(c + 1));  // deg includes self-loop
  }
  if (i == 0) row_ptr[n] = E;
}

__global__ void k_place(const int* __restrict__ ei, int* __restrict__ cursor,
                        const float* __restrict__ dinv, int* __restrict__ src_sorted,
                        float* __restrict__ w_sorted, int E) {
  int e = blockIdx.x * blockDim.x + threadIdx.x;
  if (e < E) {
    int s = ei[e], d = ei[E + e];
    int slot = atomicAdd(&cursor[d], 1);
    src_sorted[slot] = s;
    w_sorted[slot] = dinv[s] * dinv[d];
  }
}

// ---------------- fused: perturbAll (blocks 0..770) + agg_px (rest) ----------------
__global__ __launch_bounds__(256) void k_pxper(const float* __restrict__ W1, const float* __restrict__ b1,
                                               const float* __restrict__ W2, const float* __restrict__ b2,
                                               u16* __restrict__ W1hT, float* __restrict__ b1h,
                                               u16* __restrict__ W2hT, float* __restrict__ b2h,
                                               float* __restrict__ bcat,
                                               const float* __restrict__ sigma,
                                               u32 k00, u32 k01, u32 k10, u32 k11,
                                               u32 k20, u32 k21, u32 k30, u32 k31,
                                               const u16* __restrict__ xb, u16* __restrict__ px,
                                               const int* __restrict__ rp, const int* __restrict__ src,
                                               const float* __restrict__ wst, const float* __restrict__ dinv,
                                               int n) {
  int b = blockIdx.x;
  u32 r0, r1;
  if (b < 256) {  // W1 [128][512]
    int j = b * 256 + threadIdx.x;
    tf2x32(k00, k01, 0u, (u32)j, &r0, &r1);
    float v = W1[j] + sigma[0] * bits2normal(r0 ^ r1);
    int k = j >> 9, nn = j & 511;
    W1hT[(size_t)nn * 128 + k] = f2b(v);
    return;
  }
  b -= 256;
  if (b < 2) {  // b1 [512]
    int j = b * 256 + threadIdx.x;
    tf2x32(k10, k11, 0u, (u32)j, &r0, &r1);
    b1h[j] = b1[j] + sigma[1] * bits2normal(r0 ^ r1);
    return;
  }
  b -= 2;
  if (b < 512) {  // W2 [512][256]
    int j = b * 256 + threadIdx.x;
    tf2x32(k20, k21, 0u, (u32)j, &r0, &r1);
    float v = W2[j] + sigma[2] * bits2normal(r0 ^ r1);
    int k = j >> 8, nn = j & 255;
    W2hT[(size_t)nn * 512 + k] = f2b(v);
    return;
  }
  b -= 512;
  if (b < 1) {  // b2 [256] + bcat
    int j = threadIdx.x;
    tf2x32(k30, k31, 0u, (u32)j, &r0, &r1);
    float v = b2[j] + sigma[3] * bits2normal(r0 ^ r1);
    b2h[j] = v;
    bcat[256 + j] = v;
    bcat[j] = b2[j];
    return;
  }
  b -= 1;
  // ---- agg_px part ----
  int wv = threadIdx.x >> 6, lane = threadIdx.x & 63;
  int node = b * 4 + wv;
  if (node >= n) return;
  float a0 = 0.f, a1 = 0.f;
  int s0 = rp[node], s1 = rp[node + 1];
  int s = s0;
  for (; s + 8 <= s1; s += 8) {
    u32 v[8]; float wg[8];
#pragma unroll
    for (int u = 0; u < 8; ++u) {
      int r = src[s + u];
      wg[u] = wst[s + u];
      v[u] = *((const u32*)(xb + (size_t)r * 128) + lane);
    }
#pragma unroll
    for (int u = 0; u < 8; ++u) { a0 += wg[u] * blo(v[u]); a1 += wg[u] * bhi(v[u]); }
  }
  for (; s < s1; ++s) {
    float wgt = wst[s];
    int r = src[s];
    u32 w = *((const u32*)(xb + (size_t)r * 128) + lane);
    a0 += wgt * blo(w); a1 += wgt * bhi(w);
  }
  float sw = dinv[node]; sw *= sw;
  u32 w = *((const u32*)(xb + (size_t)node * 128) + lane);
  a0 += sw * blo(w); a1 += sw * bhi(w);
  u32 o = ((u32)f2b(a0)) | (((u32)f2b(a1)) << 16);
  *((u32*)(px + (size_t)node * 128) + lane) = o;
}

// ---------------- L1 GEMM: A-resident column-loop, 8-wave 64x32 wave-tiles ----------------
// 512 threads, wave grid 2x4. A stripe (32KB) staged once; loop 4 col-blocks staging 32KB B.
// Per-wave acc 32 AGPR -> high co-residency. Epilogue: per-wave 4KB scratch in Bs.
__global__ __launch_bounds__(512) void k_mgemmL1(const u16* __restrict__ A,
                                                 const u16* __restrict__ BT0, const u16* __restrict__ BT1,
                                                 const float* __restrict__ bias0, const float* __restrict__ bias1,
                                                 u16* __restrict__ C0, u16* __restrict__ C1,
                                                 int M) {
  __shared__ u16 As[16384];
  __shared__ u16 Bs[16384];
  const u16* BT = blockIdx.y ? BT1 : BT0;
  const float* bias = blockIdx.y ? bias1 : bias0;
  u16* C = blockIdx.y ? C1 : C0;
  const int t = threadIdx.x;           // 0..511
  const int w = t >> 6, lane = t & 63; // 8 waves
  const int brow = blockIdx.x * 128;
  const int wr = w >> 2, wc = w & 3;   // 2x4 wave grid: 64-row x 32-col tiles

  // stage A stripe: 32 x 1KB units across 8 waves
#pragma unroll
  for (int j = 0; j < 4; ++j) {
    int c = j * 8 + w;              // 1KB unit, wave-uniform
    int lc = c * 64 + lane;         // chunk index 0..2047
    int row = lc >> 4, ch = lc & 15;
    int chs = ch ^ (row & 15);
    int ar = brow + row; if (ar > M - 1) ar = M - 1;
    __builtin_amdgcn_global_load_lds(
        (const __attribute__((address_space(1))) void*)(A + (size_t)ar * 128 + chs * 8),
        (__attribute__((address_space(3))) void*)(As + c * 512), 16, 0, 0);
  }

  for (int cb = 0; cb < 4; ++cb) {
    int bcol = cb * 128;
#pragma unroll
    for (int j = 0; j < 4; ++j) {
      int c = j * 8 + w;
      int lc = c * 64 + lane;
      int row = lc >> 4, ch = lc & 15;
      int chs = ch ^ (row & 15);
      __builtin_amdgcn_global_load_lds(
          (const __attribute__((address_space(1))) void*)(BT + (size_t)(bcol + row) * 128 + chs * 8),
          (__attribute__((address_space(3))) void*)(Bs + c * 512), 16, 0, 0);
    }
    __syncthreads();

    f32x4 acc[4][2];
#pragma unroll
    for (int m = 0; m < 4; ++m)
#pragma unroll
      for (int n = 0; n < 2; ++n) acc[m][n] = (f32x4){0.f, 0.f, 0.f, 0.f};

#pragma unroll
    for (int kk = 0; kk < 4; ++kk) {
      int ch = kk * 4 + (lane >> 4);
      bf16x8 af[4], bb[2];
#pragma unroll
      for (int m = 0; m < 4; ++m) {
        int row = wr * 64 + m * 16 + (lane & 15);
        af[m] = *(const bf16x8*)(As + row * 128 + ((ch ^ (row & 15)) << 3));
      }
#pragma unroll
      for (int n = 0; n < 2; ++n) {
        int row = wc * 32 + n * 16 + (lane & 15);
        bb[n] = *(const bf16x8*)(Bs + row * 128 + ((ch ^ (row & 15)) << 3));
      }
#pragma unroll
      for (int m = 0; m < 4; ++m)
#pragma unroll
        for (int n = 0; n < 2; ++n)
          acc[m][n] = __builtin_amdgcn_mfma_f32_16x16x32_bf16(af[m], bb[n], acc[m][n], 0, 0, 0);
    }
    __syncthreads();  // B reads done -> epilogue may overwrite Bs

    // epilogue: per-wave 64x32 scratch (4KB) in Bs, then coalesced stores
    u16* wlds = Bs + w * 2048;
#pragma unroll
    for (int m = 0; m < 4; ++m) {
      int lr0 = m * 16 + (lane >> 4) * 4;
#pragma unroll
      for (int n = 0; n < 2; ++n) {
        int lc = n * 16 + (lane & 15);
        float bv = bias[bcol + wc * 32 + lc];
        int chunk = lc >> 3, wi = lc & 7;
#pragma unroll
        for (int q = 0; q < 4; ++q) {
          int lr = lr0 + q;
          float v = fmaxf(acc[m][n][q] + bv, 0.0f);  // RELU (L1 always)
          wlds[lr * 32 + ((chunk ^ (lr & 3)) << 3) + wi] = f2b(v);
        }
      }
    }
    int sc = lane & 3;
#pragma unroll
    for (int i = 0; i < 4; ++i) {
      int lr = i * 16 + (lane >> 2);
      int gr = brow + wr * 64 + lr;
      if (gr < M) {
        uint4 vv = *(const uint4*)(wlds + lr * 32 + ((sc ^ (lr & 3)) << 3));
        *(uint4*)(C + (size_t)gr * 512 + bcol + wc * 32 + sc * 8) = vv;
      }
    }
    __syncthreads();  // epilogue reads done -> next cb may overwrite Bs
  }
}

// ---------------- MFMA tile body: 8-wave (512t), 64x32 wave-tiles (L2 + decoder) ----------------
template <bool RELU, bool BIAS>
__device__ inline void mgemm_tile8(u16* __restrict__ As, u16* __restrict__ Bs,
                                   const u16* __restrict__ A, const u16* __restrict__ BT,
                                   const float* __restrict__ bias, u16* __restrict__ C,
                                   int M, int K, int ldc, int coloff, int bx, int by) {
  const int t = threadIdx.x;           // 0..511
  const int w = t >> 6, lane = t & 63; // 8 waves
  const int brow = by * 128;
  const int bcol = bx * 128;
  const int wr = w >> 2, wc = w & 3;   // 2x4 wave grid: 64-row x 32-col tiles

  f32x4 acc[4][2];
#pragma unroll
  for (int m = 0; m < 4; ++m)
#pragma unroll
    for (int n = 0; n < 2; ++n) acc[m][n] = (f32x4){0.f, 0.f, 0.f, 0.f};

  for (int kt = 0; kt < K; kt += 64) {
#pragma unroll
    for (int j = 0; j < 2; ++j) {
      int c = j * 8 + w;              // chunk group 0..15 (wave-uniform)
      int li = c * 64 + lane;         // 16B unit index 0..1023
      int row = li >> 3, col8 = li & 7;
      int col8s = col8 ^ (row & 7);   // source swizzle
      int ar = brow + row; if (ar > M - 1) ar = M - 1;
      __builtin_amdgcn_global_load_lds(
          (const __attribute__((address_space(1))) void*)(A + (size_t)ar * K + kt + col8s * 8),
          (__attribute__((address_space(3))) void*)(As + c * 512), 16, 0, 0);
      __builtin_amdgcn_global_load_lds(
          (const __attribute__((address_space(1))) void*)(BT + (size_t)(bcol + row) * K + kt + col8s * 8),
          (__attribute__((address_space(3))) void*)(Bs + c * 512), 16, 0, 0);
    }
    __syncthreads();
    bf16x8 af[4][2], bb[2][2];
#pragma unroll
    for (int kk = 0; kk < 2; ++kk) {
      int ch = kk * 4 + (lane >> 4);
      int chs = ch ^ (lane & 7);
#pragma unroll
      for (int m = 0; m < 4; ++m)
        af[m][kk] = *(const bf16x8*)(As + (wr * 64 + m * 16 + (lane & 15)) * 64 + chs * 8);
#pragma unroll
      for (int n = 0; n < 2; ++n)
        bb[n][kk] = *(const bf16x8*)(Bs + (wc * 32 + n * 16 + (lane & 15)) * 64 + chs * 8);
    }
#pragma unroll
    for (int kk = 0; kk < 2; ++kk)
#pragma unroll
      for (int m = 0; m < 4; ++m)
#pragma unroll
        for (int n = 0; n < 2; ++n)
          acc[m][n] = __builtin_amdgcn_mfma_f32_16x16x32_bf16(af[m][kk], bb[n][kk], acc[m][n], 0, 0, 0);
    __syncthreads();
  }

  // epilogue: per-wave 64x32 bf16 scratch (4KB) in As/Bs regions, then coalesced stores
  u16* wlds = ((w & 4) ? Bs : As) + (w & 3) * 2048;
#pragma unroll
  for (int m = 0; m < 4; ++m) {
    int lr0 = m * 16 + (lane >> 4) * 4;
#pragma unroll
    for (int n = 0; n < 2; ++n) {
      int lc = n * 16 + (lane & 15);
      float bv = BIAS ? bias[bcol + wc * 32 + lc] : 0.0f;
      int chunk = lc >> 3, wi = lc & 7;
#pragma unroll
      for (int q = 0; q < 4; ++q) {
        int lr = lr0 + q;
        float v = acc[m][n][q] + bv;
        if (RELU) v = fmaxf(v, 0.0f);
        wlds[lr * 32 + ((chunk ^ (lr & 3)) << 3) + wi] = f2b(v);
      }
    }
  }
  int sc = lane & 3;
#pragma unroll
  for (int i = 0; i < 4; ++i) {
    int lr = i * 16 + (lane >> 2);
    int gr = brow + wr * 64 + lr;
    if (gr < M) {
      uint4 vv = *(const uint4*)(wlds + lr * 32 + ((sc ^ (lr & 3)) << 3));
      *(uint4*)(C + (size_t)gr * ldc + coloff + bcol + wc * 32 + sc * 8) = vv;
    }
  }
}

// dual-branch GEMM (L2): blockIdx.z selects branch; 512 threads
template <bool RELU, bool BIAS>
__global__ __launch_bounds__(512) void k_mgemm2(const u16* A0, const u16* A1,
                                                const u16* BT0, const u16* BT1,
                                                const float* bias0, const float* bias1,
                                                u16* C0, u16* C1,
                                                int M, int K, int ldc, int co0, int co1) {
  __shared__ u16 As[8192];
  __shared__ u16 Bs[8192];
  int z = blockIdx.z;
  mgemm_tile8<RELU, BIAS>(As, Bs, z ? A1 : A0, z ? BT1 : BT0, z ? bias1 : bias0,
                          z ? C1 : C0, M, K, ldc, z ? co1 : co0, blockIdx.x, blockIdx.y);
}

// single-branch GEMM (decoder); 512 threads
__global__ __launch_bounds__(512) void k_mgemm1(const u16* __restrict__ A, const u16* __restrict__ BT,
                                                u16* __restrict__ C, int M) {
  __shared__ u16 As[8192];
  __shared__ u16 Bs[8192];
  mgemm_tile8<false, false>(As, Bs, A, BT, nullptr, C, M, 256, 128, 0, 0, blockIdx.x);
}

// ---------------- merged layer-2 agg (4-deep unroll) ----------------
__global__ __launch_bounds__(256) void k_agg512(const u16* __restrict__ ycat,
                                                float* __restrict__ zc, u16* __restrict__ zcb,
                                                float* __restrict__ zh,
                                                const int* __restrict__ rp, const int* __restrict__ src,
                                                const float* __restrict__ wst, const float* __restrict__ dinv,
                                                const float* __restrict__ bcat, int n) {
  int wv = threadIdx.x >> 6, lane = threadIdx.x & 63;
  int node = blockIdx.x * 4 + wv;
  if (node >= n) return;
  float acc[8] = {};
  int s0 = rp[node], s1 = rp[node + 1];
  int s = s0;
  for (; s + 4 <= s1; s += 4) {
    uint4 v[4]; float wg[4];
#pragma unroll
    for (int u = 0; u < 4; ++u) {
      int r = src[s + u];
      wg[u] = wst[s + u];
      v[u] = *((const uint4*)(ycat + (size_t)r * 512) + lane);
    }
#pragma unroll
    for (int u = 0; u < 4; ++u)
#pragma unroll
      for (int q = 0; q < 4; ++q) {
        u32 word = ((const u32*)&v[u])[q];
        acc[2 * q]     += wg[u] * blo(word);
        acc[2 * q + 1] += wg[u] * bhi(word);
      }
  }
  for (; s < s1; ++s) {
    float wgt = wst[s];
    int r = src[s];
    uint4 v = *((const uint4*)(ycat + (size_t)r * 512) + lane);
#pragma unroll
    for (int q = 0; q < 4; ++q) {
      u32 word = ((const u32*)&v)[q];
      acc[2 * q]     += wgt * blo(word);
      acc[2 * q + 1] += wgt * bhi(word);
    }
  }
  float sw = dinv[node]; sw *= sw;
  uint4 v = *((const uint4*)(ycat + (size_t)node * 512) + lane);
#pragma unroll
  for (int q = 0; q < 4; ++q) {
    u32 word = ((const u32*)&v)[q];
    acc[2 * q]     += sw * blo(word);
    acc[2 * q + 1] += sw * bhi(word);
  }
  int f0 = lane * 8;
#pragma unroll
  for (int j = 0; j < 8; ++j) acc[j] += bcat[f0 + j];
  if (lane < 32) {
    float* o = zc + (size_t)node * 256 + f0;
    u16* ob = zcb + (size_t)node * 256 + f0;
#pragma unroll
    for (int j = 0; j < 8; ++j) { o[j] = acc[j]; ob[j] = f2b(acc[j]); }
  } else {
    float* o = zh + (size_t)node * 256 + (f0 - 256);
#pragma unroll
    for (int j = 0; j < 8; ++j) o[j] = acc[j];
  }
}

// ---------------- pooling helpers ----------------
__device__ inline int lbound(const int* a, int n, int v) {
  int lo = 0, hi = n;
  while (lo < hi) { int mid = (lo + hi) >> 1; if (a[mid] < v) lo = mid + 1; else hi = mid; }
  return lo;
}

#define POOL_NCH 32

__global__ __launch_bounds__(256) void k_poolpart2(const float* __restrict__ zc,
                                                   const float* __restrict__ zh,
                                                   const int* __restrict__ batch,
                                                   float* __restrict__ psum, float* __restrict__ pmax,
                                                   int n) {
  int g = blockIdx.x, yy = blockIdx.y;
  int half = (yy >= POOL_NCH) ? 1 : 0;
  int ch = yy - half * POOL_NCH;
  const float* z = half ? zh : zc;
  __shared__ int ss, se;
  if (threadIdx.x == 0) { ss = lbound(batch, n, g); se = lbound(batch, n, g + 1); }
  __syncthreads();
  int start = ss, len = se - ss;
  int c0 = start + (int)((long long)len * ch / POOL_NCH);
  int c1 = start + (int)((long long)len * (ch + 1) / POOL_NCH);
  int f = threadIdx.x;
  float acc = 0.0f, mx = -INFINITY;
  for (int i = c0; i < c1; ++i) {
    float v = z[(size_t)i * 256 + f];
    acc += v;
    mx = fmaxf(mx, v);
  }
  size_t o = ((size_t)(half * 64 + g) * POOL_NCH + ch) * 256 + f;
  psum[o] = acc;
  pmax[o] = mx;
}

// ---------------- fused: agg_dec (blocks < ab) + pool_final2 (rest) ----------------
__global__ __launch_bounds__(256) void k_finaldec(const u16* __restrict__ yd, float* __restrict__ xhat,
                                                  const int* __restrict__ rp, const int* __restrict__ src,
                                                  const float* __restrict__ wst, const float* __restrict__ dinv,
                                                  const float* __restrict__ bd, int n, int ab,
                                                  const float* __restrict__ psum, const float* __restrict__ pmax,
                                                  const int* __restrict__ batch,
                                                  float* __restrict__ z_g, float* __restrict__ zhat_g,
                                                  float* __restrict__ gcat) {
  if (blockIdx.x < ab) {
    int wv = threadIdx.x >> 6, lane = threadIdx.x & 63;
    int node = blockIdx.x * 4 + wv;
    if (node >= n) return;
    float a0 = 0.f, a1 = 0.f;
    int s0 = rp[node], s1 = rp[node + 1];
    int s = s0;
    for (; s + 8 <= s1; s += 8) {
      u32 v[8]; float wg[8];
#pragma unroll
      for (int u = 0; u < 8; ++u) {
        int r = src[s + u];
        wg[u] = wst[s + u];
        v[u] = *((const u32*)(yd + (size_t)r * 128) + lane);
      }
#pragma unroll
      for (int u = 0; u < 8; ++u) { a0 += wg[u] * blo(v[u]); a1 += wg[u] * bhi(v[u]); }
    }
    for (; s < s1; ++s) {
      float wgt = wst[s];
      int r = src[s];
      u32 w = *((const u32*)(yd + (size_t)r * 128) + lane);
      a0 += wgt * blo(w); a1 += wgt * bhi(w);
    }
    float sw = dinv[node]; sw *= sw;
    u32 w = *((const u32*)(yd + (size_t)node * 128) + lane);
    a0 += sw * blo(w); a1 += sw * bhi(w);
    float2 o;
    o.x = a0 + bd[lane * 2];
    o.y = a1 + bd[lane * 2 + 1];
    *((float2*)(xhat + (size_t)node * 128) + lane) = o;
    return;
  }
  int gg = blockIdx.x - ab, f = threadIdx.x;  // 0..127
  int g = gg & 63, half = gg >> 6;
  float s = 0.0f, m = -INFINITY;
#pragma unroll 4
  for (int c = 0; c < POOL_NCH; ++c) {
    size_t o = ((size_t)gg * POOL_NCH + c) * 256 + f;
    s += psum[o];
    m = fmaxf(m, pmax[o]);
  }
  __shared__ int ss, se;
  if (threadIdx.x == 0) { ss = lbound(batch, n, g); se = lbound(batch, n, g + 1); }
  __syncthreads();
  int cnt = se - ss;
  float mean = s / fmaxf((float)cnt, 1.0f);
  float mxo = (cnt > 0) ? m : 0.0f;
  float* zg = half ? zhat_g : z_g;
  zg[(size_t)g * 512 + f] = mean;
  zg[(size_t)g * 512 + 256 + f] = mxo;
  gcat[(size_t)gg * 512 + f] = mean;
  gcat[(size_t)gg * 512 + 256 + f] = mxo;
}

// ---------------- projection head: full 3-layer MLP, one block per row ----------------
__global__ __launch_bounds__(256) void k_proj(const float* __restrict__ gcat,
                                              const float* __restrict__ P1w, const float* __restrict__ P1b,
                                              const float* __restrict__ P2w, const float* __restrict__ P2b,
                                              const float* __restrict__ P3w, const float* __restrict__ P3b,
                                              float* __restrict__ outg) {
  __shared__ float gi[512];
  __shared__ float h1[256];
  __shared__ float h2[128];
  int r = blockIdx.x;  // 0..127
  int t = threadIdx.x;
  gi[t] = gcat[(size_t)r * 512 + t];
  gi[t + 256] = gcat[(size_t)r * 512 + 256 + t];
  __syncthreads();
  float a = 0.f;
#pragma unroll 8
  for (int k = 0; k < 512; ++k) a += gi[k] * P1w[k * 256 + t];
  h1[t] = fmaxf(a + P1b[t], 0.f);
  __syncthreads();
  if (t < 128) {
    float a2 = 0.f;
#pragma unroll 8
    for (int k = 0; k < 256; ++k) a2 += h1[k] * P2w[k * 128 + t];
    h2[t] = fmaxf(a2 + P2b[t], 0.f);
  }
  __syncthreads();
  if (t < 64) {
    float a3 = 0.f;
#pragma unroll 8
    for (int k = 0; k < 128; ++k) a3 += h2[k] * P3w[k * 64 + t];
    outg[(size_t)r * 64 + t] = a3 + P3b[t];
  }
}

// ---------------- launch ----------------
extern "C" void kernel_launch(void* const* d_in, const int* in_sizes, int n_in,
                              void* d_out, int out_size, void* d_ws, size_t ws_size,
                              hipStream_t stream) {
  const float* x   = (const float*)d_in[0];
  const int*   ei  = (const int*)d_in[1];
  const int*   bat = (const int*)d_in[2];
  const float* W1  = (const float*)d_in[4];
  const float* b1  = (const float*)d_in[5];
  const float* W2  = (const float*)d_in[6];
  const float* b2  = (const float*)d_in[7];
  const float* Wd  = (const float*)d_in[8];
  const float* bd  = (const float*)d_in[9];
  const float* P1w = (const float*)d_in[10];
  const float* P1b = (const float*)d_in[11];
  const float* P2w = (const float*)d_in[12];
  const float* P2b = (const float*)d_in[13];
  const float* P3w = (const float*)d_in[14];
  const float* P3b = (const float*)d_in[15];

  const int N = in_sizes[0] / 128;  // 50000
  const int E = in_sizes[1] / 2;    // 400000
  const int B = 64;
  const int NB = (N + 1023) / 1024;

  char* w = (char*)d_ws;
  auto carve = [&](size_t bytes) -> void* {
    void* p = (void*)w;
    w += (bytes + 255) & ~(size_t)255;
    return p;
  };
  int*    cnt        = (int*)carve((size_t)N * 4);
  int*    row_ptr    = (int*)carve((size_t)(N + 1) * 4);
  int*    cursor     = (int*)carve((size_t)N * 4);
  float*  dinv       = (float*)carve((size_t)N * 4);
  int*    incl       = (int*)carve((size_t)N * 4);
  int*    bsum       = (int*)carve((size_t)1024 * 4);
  int*    src_sorted = (int*)carve((size_t)E * 4);
  float*  w_sorted   = (float*)carve((size_t)E * 4);
  float*  sigma      = (float*)carve(256);
  double* psd        = (double*)carve((size_t)64 * 2 * 8);
  float*  b1h        = (float*)carve((size_t)512 * 4);
  float*  b2h        = (float*)carve((size_t)256 * 4);
  float*  bcat       = (float*)carve((size_t)512 * 4);
  u16*    W1T        = (u16*)carve((size_t)128 * 512 * 2);
  u16*    W2T        = (u16*)carve((size_t)512 * 256 * 2);
  u16*    WdT        = (u16*)carve((size_t)256 * 128 * 2);
  u16*    W1hT       = (u16*)carve((size_t)128 * 512 * 2);
  u16*    W2hT       = (u16*)carve((size_t)512 * 256 * 2);
  u16*    xb         = (u16*)carve((size_t)N * 128 * 2);
  u16*    px         = (u16*)carve((size_t)N * 128 * 2);
  u16*    z1c        = (u16*)carve((size_t)N * 512 * 2);   // clean L1 out
  u16*    z1p        = (u16*)carve((size_t)N * 512 * 2);   // pert L1 out
  u16*    ycat       = (u16*)carve((size_t)N * 512 * 2);   // [y_clean | y_pert]; later aliased yd
  u16*    znb        = (u16*)carve((size_t)N * 256 * 2);   // bf16 z_node (decoder A)
  float*  gcat       = (float*)carve((size_t)128 * 512 * 4);
  float*  psum       = (float*)carve((size_t)2 * B * POOL_NCH * 256 * 4);
  float*  pmax       = (float*)carve((size_t)2 * B * POOL_NCH * 256 * 4);
  u16*    yd         = ycat;  // alias: ycat dead after k_agg512

  float* out       = (float*)d_out;
  float* z_node    = out;
  float* z_g       = z_node + (size_t)N * 256;
  float* zhat_node = z_g + (size_t)B * 512;
  float* zhat_g    = zhat_node + (size_t)N * 256;
  float* h_g       = zhat_g + (size_t)B * 512;           // h_g||hhat_g contiguous
  float* x_hat     = h_g + (size_t)2 * B * 64;

  // nk = split(key(42), 4): nk[i] = threefry(key, (0, i))
  u32 nk[4][2];
  for (u32 i = 0; i < 4; ++i) tf2x32(0u, 42u, 0u, i, &nk[i][0], &nk[i][1]);

  const int c1 = (E + 255) / 256;
  const int n4b = (N * 128 / 4 + 255) / 256;
  const int prepABlocks = c1 + 64 + 256 + 512 + 128 + n4b;
  const int aggBlocks = (N + 3) / 4;
  const int MB = (N + 127) / 128;

  // 1-2: prep
  hipMemsetAsync(cnt, 0, (size_t)N * 4, stream);
  k_prepA<<<prepABlocks, 256, 0, stream>>>(ei, cnt, E, W1, b1, W2, b2, psd,
                                           Wd, W1T, W2T, WdT, x, xb, N, c1);
  // 3-6: CSR build
  k_scan_local<<<NB, 1024, 0, stream>>>(cnt, incl, bsum, N);
  k_small2<<<2, 256, 0, stream>>>(bsum, NB, psd, sigma);
  k_scan_final<<<NB, 1024, 0, stream>>>(cnt, incl, bsum, row_ptr, cursor, dinv, N, E);
  k_place<<<(E + 255) / 256, 256, 0, stream>>>(ei, cursor, dinv, src_sorted, w_sorted, E);

  // 7: perturb + agg_px fused
  k_pxper<<<771 + aggBlocks, 256, 0, stream>>>(W1, b1, W2, b2, W1hT, b1h, W2hT, b2h, bcat, sigma,
                                               nk[0][0], nk[0][1], nk[1][0], nk[1][1],
                                               nk[2][0], nk[2][1], nk[3][0], nk[3][1],
                                               xb, px, row_ptr, src_sorted, w_sorted, dinv, N);

  // 8: L1 both branches, A-resident column-loop, 8-wave tiles
  k_mgemmL1<<<dim3(MB, 2), 512, 0, stream>>>(px, W1T, W1hT, b1, b1h, z1c, z1p, N);

  // 9: L2 both branches -> ycat [clean | pert], 8-wave tiles
  k_mgemm2<false, false><<<dim3(2, MB, 2), 512, 0, stream>>>(z1c, z1p, W2T, W2hT, nullptr, nullptr,
                                                             ycat, ycat, N, 512, 512, 0, 256);

  // 10: merged propagation
  k_agg512<<<aggBlocks, 256, 0, stream>>>(ycat, z_node, znb, zhat_node,
                                          row_ptr, src_sorted, w_sorted, dinv, bcat, N);

  // 11: decoder GEMM (8-wave)
  k_mgemm1<<<MB, 512, 0, stream>>>(znb, WdT, yd, N);
  // 12: pool stage-1
  dim3 pgrid(B, 2 * POOL_NCH);
  k_poolpart2<<<pgrid, 256, 0, stream>>>(z_node, zhat_node, bat, psum, pmax, N);

  // 13: decoder propagation + pool stage-2
  k_finaldec<<<aggBlocks + 128, 256, 0, stream>>>(yd, x_hat, row_ptr, src_sorted, w_sorted, dinv, bd,
                                                  N, aggBlocks, psum, pmax, bat, z_g, zhat_g, gcat);

  // 14: projection heads
  k_proj<<<128, 256, 0, stream>>>(gcat, P1w, P1b, P2w, P2b, P3w, P3b, h_g);
}